// Round 1
// baseline (482.778 us; speedup 1.0000x reference)
//
#include <hip/hip_runtime.h>
#include <hip/hip_bf16.h>

typedef __attribute__((ext_vector_type(8))) short bf16x8;
typedef __attribute__((ext_vector_type(4))) float f32x4;
typedef unsigned short u16;
typedef const __attribute__((address_space(1))) void as1_void;
typedef __attribute__((address_space(3))) void as3_void;

// dims: B=1024 N=60 D=5 Fa=62 Fb=6 width=128; conv KSZ=16 FILT=128 Tout=45
// ws layout (bytes)
static constexpr size_t OFF_BN   = 0;                      // scale[4][128], shift[4][128] = 4096 B
static constexpr size_t OFF_BSUM = 4096;                   // 61440*6*4 = 1474560 B
static constexpr size_t OFF_WCT  = OFF_BSUM + 1474560;     // 128*2048*2 = 524288 B (16B aligned)
static constexpr size_t OFF_X1   = OFF_WCT + 524288;       // 61440*128*2 = 15728640 B
static constexpr size_t OFF_X3   = OFF_X1 + 15728640;      // 15728640 B
// total ~33.5 MB ; x2 lives in d_out (bf16, 15.7MB < 23.6MB, dead before conv writes)

// ---------------- prep: BN scale/shift ----------------
__global__ __launch_bounds__(512) void bn_prep(
    const float* g1, const float* be1, const float* m1, const float* v1,
    const float* g2, const float* be2, const float* m2, const float* v2,
    const float* g3, const float* be3, const float* m3, const float* v3,
    const float* g4, const float* be4, const float* m4, const float* v4,
    float* __restrict__ scale, float* __restrict__ shift) {
  int t = threadIdx.x;                   // 512 threads exactly
  const float* gs[4] = {g1, g2, g3, g4};
  const float* bs[4] = {be1, be2, be3, be4};
  const float* ms[4] = {m1, m2, m3, m4};
  const float* vs[4] = {v1, v2, v3, v4};
  int l = t >> 7, ch = t & 127;
  float g = gs[l][ch], be = bs[l][ch], m = ms[l][ch], v = vs[l][ch];
  float sc = g / sqrtf(v + 1e-3f);       // keras BN epsilon
  scale[t] = sc;
  shift[t] = be - m * sc;
}

// ---------------- prep: bond sums [B*N][6] ----------------
__global__ __launch_bounds__(256) void bsum_prep(const float* __restrict__ bonds,
                                                 float* __restrict__ bsum) {
  int a = blockIdx.x * 256 + threadIdx.x;   // 61440 atoms
  const float* p = bonds + (size_t)a * 30;
  float s[6] = {0.f, 0.f, 0.f, 0.f, 0.f, 0.f};
  #pragma unroll
  for (int d = 0; d < 5; ++d)
    #pragma unroll
    for (int j = 0; j < 6; ++j) s[j] += p[d * 6 + j];
  #pragma unroll
  for (int j = 0; j < 6; ++j) bsum[(size_t)a * 6 + j] = s[j];
}

// ---------------- prep: Wc [16][128][128] f32 -> Wct [f][2048] bf16 ----------------
__global__ __launch_bounds__(512) void wct_prep(const float* __restrict__ Wc,
                                                u16* __restrict__ wct) {
  int t = blockIdx.x * 512 + threadIdx.x;   // 32768
  int f = t >> 8, kf0 = (t & 255) << 3;
  bf16x8 v;
  #pragma unroll
  for (int i = 0; i < 8; ++i) {
    __hip_bfloat16 h = __float2bfloat16(Wc[(size_t)(kf0 + i) * 128 + f]);
    v[i] = *(short*)&h;
  }
  *reinterpret_cast<bf16x8*>(&wct[(size_t)f * 2048 + kf0]) = v;
}

// ---------------- NGF layer: gather + per-degree dense + BN + ReLU ----------------
// Strategy: GEMV with W[deg=5] for ALL rows (wave-uniform W -> SGPR-operand FMAs),
// then recompute the ~8% deg!=5 rows exactly. One block per molecule b.
template <int CIN, int FIN, bool IN_BF16>
__global__ __launch_bounds__(256, 2) void ngf_layer(
    const void* __restrict__ xin_g, const int* __restrict__ edges_g,
    const float* __restrict__ bsum, const float* __restrict__ W,
    const float* __restrict__ bias, const float* __restrict__ bnscale,
    const float* __restrict__ bnshift, u16* __restrict__ xout) {
  constexpr int FINP = FIN + 1;              // odd stride -> conflict-free lane=n reads
  constexpr int CW = (CIN <= 64) ? 64 : 128;
  __shared__ float buf0[60 * 129];           // xin (stride CIN) then out (stride 129)
  __shared__ float feats[64 * FINP];
  __shared__ int eds[300];
  __shared__ int degs[64];
  __shared__ unsigned long long flagmask;
  const int b = blockIdx.x, tid = threadIdx.x;
  const int lane = tid & 63;
  const int wid = __builtin_amdgcn_readfirstlane(tid >> 6);

  for (int i = tid; i < 300; i += 256) eds[i] = edges_g[b * 300 + i];
  if (IN_BF16) {
    const u16* xg = (const u16*)xin_g + (size_t)b * 60 * CIN;
    for (int i = tid; i < 60 * CIN; i += 256) {
      u16 raw = xg[i];
      buf0[i] = __bfloat162float(*(const __hip_bfloat16*)&raw);
    }
  } else {
    const float* xg = (const float*)xin_g + (size_t)b * 60 * CIN;
    for (int i = tid; i < 60 * CIN; i += 256) buf0[i] = xg[i];
  }
  for (int i = tid; i < 360; i += 256)
    feats[(i / 6) * FINP + CIN + (i % 6)] = bsum[(size_t)b * 360 + i];
  for (int i = tid; i < 4 * FINP; i += 256)          // zero pad rows 60..63
    feats[(60 + i / FINP) * FINP + (i % FINP)] = 0.f;
  __syncthreads();

  // degrees + flagged mask (wave 0, in-register)
  if (tid < 64) {
    int dg = 5;
    if (tid < 60) {
      dg = 0;
      #pragma unroll
      for (int d = 0; d < 5; ++d) dg += (eds[tid * 5 + d] >= 0);
    }
    degs[tid] = dg;
    unsigned long long m = __ballot(tid < 60 && dg != 5);
    if (tid == 0) flagmask = m;
  }
  // feats atom part: self + neighbor gather-sum (e is wave-uniform -> LDS broadcast)
  for (int i = tid; i < 60 * CW; i += 256) {
    int n = i / CW, c = i % CW;
    if (c < CIN) {
      float v = buf0[n * CIN + c];
      #pragma unroll
      for (int d = 0; d < 5; ++d) {
        int e = eds[n * 5 + d];
        if (e >= 0) v += buf0[e * CIN + c];
      }
      feats[n * FINP + c] = v;
    }
  }
  __syncthreads();

  // main GEMV with W[5]: lane = atom row, wave owns 32 output channels.
  // W5 row address is wave-uniform -> s_load; v_fmac(acc, s_w, v_x).
  const int f0 = wid * 32;
  const float* __restrict__ W5 = W + 5 * FIN * 128;
  const float* __restrict__ b5 = bias + 5 * 128;
  float acc[32];
  #pragma unroll
  for (int j = 0; j < 32; ++j) acc[j] = b5[f0 + j];
  #pragma unroll 2
  for (int c = 0; c < FIN; ++c) {
    float x = feats[lane * FINP + c];
    const float* wr = W5 + c * 128 + f0;
    #pragma unroll
    for (int j = 0; j < 32; ++j) acc[j] = __builtin_fmaf(x, wr[j], acc[j]);
  }
  if (lane < 60) {
    #pragma unroll
    for (int j = 0; j < 32; ++j) buf0[lane * 129 + f0 + j] = acc[j];
  }
  __syncthreads();

  // correction: recompute rows with deg != 5 (~8% of atoms), one wave per atom
  {
    unsigned long long m = flagmask;
    int idx = 0;
    while (m) {
      int n = __ffsll((long long)m) - 1;
      m &= m - 1;
      if ((idx++ & 3) == wid) {
        int dg = degs[n];
        const float* __restrict__ Wd = W + dg * FIN * 128;
        const float* __restrict__ bd = bias + dg * 128;
        float a0 = bd[lane], a1 = bd[lane + 64];
        for (int c = 0; c < FIN; ++c) {
          float x = feats[n * FINP + c];
          a0 = __builtin_fmaf(x, Wd[c * 128 + lane], a0);
          a1 = __builtin_fmaf(x, Wd[c * 128 + lane + 64], a1);
        }
        buf0[n * 129 + lane] = a0;
        buf0[n * 129 + lane + 64] = a1;
      }
    }
  }
  __syncthreads();

  // BN + ReLU + bf16 store
  u16* xo = xout + (size_t)b * 60 * 128;
  for (int i = tid; i < 60 * 128; i += 256) {
    int n = i >> 7, f = i & 127;
    float y = buf0[n * 129 + f] * bnscale[f] + bnshift[f];
    y = fmaxf(y, 0.f);
    __hip_bfloat16 h = __float2bfloat16(y);
    xo[i] = *(u16*)&h;
  }
}

// ---------------- Conv1D (implicit GEMM, bf16 MFMA) + BN + ReLU ----------------
// A[t][kf] = x3[b][t + kf/128][kf%128]: whole K fits in LDS -> barrier-free K-loop.
// B fragments read directly from L2-resident Wct[f][2048].
__global__ __launch_bounds__(512, 2) void conv_bn(
    const u16* __restrict__ x3, const u16* __restrict__ wct,
    const float* __restrict__ bnscale, const float* __restrict__ bnshift,
    float* __restrict__ out) {
  __shared__ u16 A[4 * 64 * 128];   // 64 KB, 16B-unit XOR-swizzled rows
  const int tid = threadIdx.x;
  const int lane = tid & 63;
  const int wid = __builtin_amdgcn_readfirstlane(tid >> 6);
  const int b0 = blockIdx.x * 4;

  // stage 4 molecules (64 rows each; rows>=60 clamp-read row 59, values unused).
  // rule 21: linear LDS dest + inverse-swizzled per-lane global source.
  for (int op = wid; op < 64; op += 8) {
    int off = op * 1024 + lane * 16;      // byte offset in A
    int bl = off >> 14;
    int row = (off >> 8) & 63;
    int unit = (off >> 4) & 15;
    int sunit = unit ^ (row & 7);
    int rowc = row < 60 ? row : 59;
    const u16* src = x3 + (((size_t)(b0 + bl) * 60 + rowc) << 7) + sunit * 8;
    __builtin_amdgcn_global_load_lds((as1_void*)src,
                                     (as3_void*)((char*)A + op * 1024), 16, 0, 0);
  }
  __syncthreads();

  const int wr = wid >> 1;   // molecule within block
  const int wc = wid & 1;    // filter half
  f32x4 acc[3][4];
  #pragma unroll
  for (int rt = 0; rt < 3; ++rt)
    #pragma unroll
    for (int ct = 0; ct < 4; ++ct) acc[rt][ct] = (f32x4){0.f, 0.f, 0.f, 0.f};

  for (int ks = 0; ks < 64; ++ks) {
    int rowadd = ks >> 2;
    int unit = ((ks & 3) << 2) + (lane >> 4);
    bf16x8 a[3], bfr[4];
    #pragma unroll
    for (int rt = 0; rt < 3; ++rt) {
      int arow = rt * 16 + (lane & 15) + rowadd;       // <= 62
      int uo = unit ^ (arow & 7);                      // read-side swizzle
      a[rt] = *reinterpret_cast<const bf16x8*>(&A[wr * 8192 + arow * 128 + uo * 8]);
    }
    const u16* wp = wct + ks * 32 + ((lane >> 4) << 3);
    #pragma unroll
    for (int ct = 0; ct < 4; ++ct) {
      int f = (wc * 4 + ct) * 16 + (lane & 15);
      bfr[ct] = *reinterpret_cast<const bf16x8*>(wp + (size_t)f * 2048);
    }
    #pragma unroll
    for (int rt = 0; rt < 3; ++rt)
      #pragma unroll
      for (int ct = 0; ct < 4; ++ct)
        acc[rt][ct] = __builtin_amdgcn_mfma_f32_16x16x32_bf16(a[rt], bfr[ct],
                                                              acc[rt][ct], 0, 0, 0);
  }

  // epilogue: BN4 + ReLU, store f32. D layout: col=lane&15, row=(lane>>4)*4+j.
  const size_t bb = b0 + wr;
  #pragma unroll
  for (int ct = 0; ct < 4; ++ct) {
    int f = (wc * 4 + ct) * 16 + (lane & 15);
    float sc = bnscale[f], sh = bnshift[f];
    #pragma unroll
    for (int rt = 0; rt < 3; ++rt) {
      #pragma unroll
      for (int j = 0; j < 4; ++j) {
        int t = rt * 16 + ((lane >> 4) << 2) + j;
        if (t < 45) {
          float y = fmaxf(acc[rt][ct][j] * sc + sh, 0.f);
          out[(bb * 45 + t) * 128 + f] = y;
        }
      }
    }
  }
}

extern "C" void kernel_launch(void* const* d_in, const int* in_sizes, int n_in,
                              void* d_out, int out_size, void* d_ws, size_t ws_size,
                              hipStream_t stream) {
  const float* atoms = (const float*)d_in[0];
  const float* bonds = (const float*)d_in[1];
  const int*   edges = (const int*)d_in[2];
  const float* W1 = (const float*)d_in[3]; const float* b1 = (const float*)d_in[4];
  const float* W2 = (const float*)d_in[5]; const float* b2 = (const float*)d_in[6];
  const float* W3 = (const float*)d_in[7]; const float* b3 = (const float*)d_in[8];
  const float* Wc = (const float*)d_in[9];

  char* ws = (char*)d_ws;
  float* scale = (float*)(ws + OFF_BN);
  float* shift = scale + 512;
  float* bsum  = (float*)(ws + OFF_BSUM);
  u16*   wct   = (u16*)(ws + OFF_WCT);
  u16*   x1    = (u16*)(ws + OFF_X1);
  u16*   x3    = (u16*)(ws + OFF_X3);
  u16*   x2    = (u16*)d_out;   // scratch; overwritten by conv afterwards

  bn_prep<<<1, 512, 0, stream>>>(
      (const float*)d_in[10], (const float*)d_in[11], (const float*)d_in[12], (const float*)d_in[13],
      (const float*)d_in[14], (const float*)d_in[15], (const float*)d_in[16], (const float*)d_in[17],
      (const float*)d_in[18], (const float*)d_in[19], (const float*)d_in[20], (const float*)d_in[21],
      (const float*)d_in[22], (const float*)d_in[23], (const float*)d_in[24], (const float*)d_in[25],
      scale, shift);
  bsum_prep<<<240, 256, 0, stream>>>(bonds, bsum);
  wct_prep<<<64, 512, 0, stream>>>(Wc, wct);

  ngf_layer<62, 68, false><<<1024, 256, 0, stream>>>(
      atoms, edges, bsum, W1, b1, scale + 0, shift + 0, x1);
  ngf_layer<128, 134, true><<<1024, 256, 0, stream>>>(
      x1, edges, bsum, W2, b2, scale + 128, shift + 128, x2);
  ngf_layer<128, 134, true><<<1024, 256, 0, stream>>>(
      x2, edges, bsum, W3, b3, scale + 256, shift + 256, x3);
  conv_bn<<<256, 512, 0, stream>>>(x3, wct, scale + 384, shift + 384, (float*)d_out);
}

// Round 2
// 324.323 us; speedup vs baseline: 1.4886x; 1.4886x over previous
//
#include <hip/hip_runtime.h>
#include <hip/hip_bf16.h>

typedef __attribute__((ext_vector_type(8))) short bf16x8;
typedef __attribute__((ext_vector_type(4))) short short4v;
typedef __attribute__((ext_vector_type(4))) float f32x4;
typedef unsigned short u16;
typedef const __attribute__((address_space(1))) void as1_void;
typedef __attribute__((address_space(3))) void as3_void;

// dims: B=1024 N=60 D=5 Fa=62 Fb=6 width=128; conv KSZ=16 FILT=128 Tout=45
// ws layout (bytes), kept under the 33.5 MB footprint that round-1 validated
static constexpr size_t OFF_BN   = 0;                        // scale[4][128]+shift[4][128] = 4096
static constexpr size_t OFF_SH2  = 4096;                     // shift2[3][6][128] f32 = 9216
static constexpr size_t OFF_BSUM = 13312;                    // 61440*6*2 (bf16) = 737280
static constexpr size_t OFF_WT1  = 750592;                   // 6*128*96*2  = 147456
static constexpr size_t OFF_WT2  = 898048;                   // 6*128*160*2 = 245760
static constexpr size_t OFF_WT3  = 1143808;                  // 245760
static constexpr size_t OFF_WCT  = 1389568;                  // 128*2048*2 = 524288
static constexpr size_t OFF_X1   = 1913856;                  // 61440*128*2 = 15728640
static constexpr size_t OFF_X3   = 17642496;                 // 15728640 -> ends 33371136
// x2 lives in d_out (bf16 15.7MB < f32 out 23.6MB; dead before conv writes)

__device__ __forceinline__ float bf2f(u16 r) {
  union { unsigned u; float f; } cv; cv.u = ((unsigned)r) << 16; return cv.f;
}
__device__ __forceinline__ u16 f2bf(float x) {
  __hip_bfloat16 h = __float2bfloat16(x); return *(u16*)&h;
}

// ---------------- prep: BN scale/shift + per-degree folded bias ----------------
__global__ __launch_bounds__(512) void bn_prep(
    const float* g1, const float* be1, const float* m1, const float* v1,
    const float* g2, const float* be2, const float* m2, const float* v2,
    const float* g3, const float* be3, const float* m3, const float* v3,
    const float* g4, const float* be4, const float* m4, const float* v4,
    const float* bb1, const float* bb2, const float* bb3,
    float* __restrict__ scale, float* __restrict__ shift,
    float* __restrict__ shift2) {
  int t = threadIdx.x;                   // 512 threads exactly
  const float* gs[4] = {g1, g2, g3, g4};
  const float* bs[4] = {be1, be2, be3, be4};
  const float* ms[4] = {m1, m2, m3, m4};
  const float* vs[4] = {v1, v2, v3, v4};
  int l = t >> 7, ch = t & 127;
  float g = gs[l][ch], be = bs[l][ch], m = ms[l][ch], v = vs[l][ch];
  float sc = g / sqrtf(v + 1e-3f);       // keras BN epsilon
  scale[t] = sc;
  shift[t] = be - m * sc;
  __syncthreads();
  const float* bl[3] = {bb1, bb2, bb3};
  for (int i = t; i < 3 * 6 * 128; i += 512) {
    int ll = i / 768, r = i % 768, f = r & 127;   // r = d*128+f
    shift2[i] = bl[ll][r] * scale[ll * 128 + f] + shift[ll * 128 + f];
  }
}

// ---------------- prep: bond sums [B*N][6] bf16 ----------------
__global__ __launch_bounds__(256) void bsum_prep(const float* __restrict__ bonds,
                                                 u16* __restrict__ bsum) {
  int a = blockIdx.x * 256 + threadIdx.x;   // 61440 atoms
  const float* p = bonds + (size_t)a * 30;
  float s[6] = {0.f, 0.f, 0.f, 0.f, 0.f, 0.f};
  #pragma unroll
  for (int d = 0; d < 5; ++d)
    #pragma unroll
    for (int j = 0; j < 6; ++j) s[j] += p[d * 6 + j];
  #pragma unroll
  for (int j = 0; j < 6; ++j) bsum[(size_t)a * 6 + j] = f2bf(s[j]);
}

// ---------------- prep: layer W [6][FIN][128] f32 -> Wt [6][128][KP] bf16 ----------------
template <int FIN, int KP>
__global__ __launch_bounds__(256) void wt_prep(const float* __restrict__ W,
                                               u16* __restrict__ wt) {
  int t = blockIdx.x * 256 + threadIdx.x;
  if (t >= 6 * 128 * KP / 8) return;
  int k0 = (t % (KP / 8)) * 8;
  int f = (t / (KP / 8)) & 127;
  int d = t / (KP / 8 * 128);
  bf16x8 v;
  #pragma unroll
  for (int i = 0; i < 8; ++i) {
    int k = k0 + i;
    float x = (k < FIN) ? W[((size_t)d * FIN + k) * 128 + f] : 0.f;
    v[i] = (short)f2bf(x);
  }
  *reinterpret_cast<bf16x8*>(&wt[((size_t)d * 128 + f) * KP + k0]) = v;
}

// ---------------- prep: Wc [16][128][128] f32 -> Wct [f][2048] bf16 ----------------
__global__ __launch_bounds__(512) void wct_prep(const float* __restrict__ Wc,
                                                u16* __restrict__ wct) {
  int t = blockIdx.x * 512 + threadIdx.x;   // 32768
  int f = t >> 8, kf0 = (t & 255) << 3;
  bf16x8 v;
  #pragma unroll
  for (int i = 0; i < 8; ++i) v[i] = (short)f2bf(Wc[(size_t)(kf0 + i) * 128 + f]);
  *reinterpret_cast<bf16x8*>(&wct[(size_t)f * 2048 + kf0]) = v;
}

// ---------------- NGF layer: gather + per-degree MFMA GEMM + BN + ReLU ----------------
// One block per molecule. feats[64xKP] bf16 in LDS (unit-XOR swizzled);
// loop over degrees present, full 60x128 MFMA per degree, predicated store.
template <int CIN, int FIN, int KP, bool IN_BF16>
__global__ __launch_bounds__(256, 2) void ngf_mfma(
    const void* __restrict__ xin_g, const int* __restrict__ edges_g,
    const u16* __restrict__ bsum, const u16* __restrict__ wt,
    const float* __restrict__ bnscale, const float* __restrict__ shift2,
    u16* __restrict__ xout) {
  constexpr int KSTEPS = KP / 32;
  constexpr int CW = (CIN <= 64) ? 64 : 128;
  __shared__ float buf0[60 * CIN];
  __shared__ u16 featsb[64 * KP];
  __shared__ int eds[300];
  __shared__ int degs[64];
  __shared__ int presentS;
  const int b = blockIdx.x, tid = threadIdx.x;
  const int lane = tid & 63;
  const int wid = __builtin_amdgcn_readfirstlane(tid >> 6);

  // phase A: stage edges + x_in, zero feats, init present
  if (tid == 0) presentS = 0;
  for (int i = tid; i < 300; i += 256) eds[i] = edges_g[b * 300 + i];
  if (IN_BF16) {
    const bf16x8* xg = (const bf16x8*)((const u16*)xin_g + (size_t)b * 60 * CIN);
    for (int i = tid; i < 60 * CIN / 8; i += 256) {
      bf16x8 v = xg[i];
      #pragma unroll
      for (int j = 0; j < 8; ++j) buf0[i * 8 + j] = bf2f((u16)v[j]);
    }
  } else {
    const float4* xg = (const float4*)((const float*)xin_g + (size_t)b * 60 * CIN);
    for (int i = tid; i < 60 * CIN / 4; i += 256) {
      float4 v = xg[i];
      buf0[i * 4 + 0] = v.x; buf0[i * 4 + 1] = v.y;
      buf0[i * 4 + 2] = v.z; buf0[i * 4 + 3] = v.w;
    }
  }
  {
    short4v* fz = (short4v*)featsb;
    for (int i = tid; i < 64 * KP / 4; i += 256) fz[i] = (short4v){0, 0, 0, 0};
  }
  __syncthreads();

  // phase B: degrees + presence mask; gather feats (bf16, unit-swizzled)
  if (tid < 64) {
    int dg = 7;
    if (tid < 60) {
      dg = 0;
      #pragma unroll
      for (int d = 0; d < 5; ++d) dg += (eds[tid * 5 + d] >= 0);
      atomicOr(&presentS, 1 << dg);
    }
    degs[tid] = dg;
  }
  for (int i = tid; i < 60 * CW; i += 256) {
    int n = i / CW, c = i % CW;
    if (c < CIN) {
      float v = buf0[n * CIN + c];
      #pragma unroll
      for (int d = 0; d < 5; ++d) {
        int e = eds[n * 5 + d];
        if (e >= 0) v += buf0[e * CIN + c];
      }
      featsb[n * KP + ((((c >> 3) ^ ((n >> 1) & 3)) << 3) | (c & 7))] = f2bf(v);
    }
  }
  for (int i = tid; i < 360; i += 256) {
    int n = i / 6, c = CIN + (i % 6);
    featsb[n * KP + ((((c >> 3) ^ ((n >> 1) & 3)) << 3) | (c & 7))] = bsum[(size_t)b * 360 + i];
  }
  __syncthreads();

  // phase C: per-degree MFMA passes. Wave owns N-slice f0..f0+31, all 64 M rows.
  const int pres = presentS;
  const int rgrp = lane >> 4;       // 0..3 (k-group / D row group)
  const int fr = lane & 15;         // A row low / B col low
  const int f0 = wid * 32;
  u16* xo = xout + (size_t)b * 7680;

  for (int d = 0; d < 6; ++d) {
    if (!(pres & (1 << d))) continue;
    f32x4 acc[4][2];
    #pragma unroll
    for (int mt = 0; mt < 4; ++mt)
      #pragma unroll
      for (int nt = 0; nt < 2; ++nt) acc[mt][nt] = (f32x4){0.f, 0.f, 0.f, 0.f};
    const u16* __restrict__ wd = wt + (size_t)d * 128 * KP;
    #pragma unroll
    for (int ks = 0; ks < KSTEPS; ++ks) {
      const int k0 = ks * 32 + rgrp * 8;
      bf16x8 a[4], bb[2];
      #pragma unroll
      for (int mt = 0; mt < 4; ++mt) {
        int r = mt * 16 + fr;
        int u = (k0 >> 3) ^ ((r >> 1) & 3);
        a[mt] = *reinterpret_cast<const bf16x8*>(&featsb[r * KP + u * 8]);
      }
      #pragma unroll
      for (int nt = 0; nt < 2; ++nt) {
        int f = f0 + nt * 16 + fr;
        bb[nt] = *reinterpret_cast<const bf16x8*>(&wd[(size_t)f * KP + k0]);
      }
      #pragma unroll
      for (int mt = 0; mt < 4; ++mt)
        #pragma unroll
        for (int nt = 0; nt < 2; ++nt)
          acc[mt][nt] = __builtin_amdgcn_mfma_f32_16x16x32_bf16(a[mt], bb[nt],
                                                                acc[mt][nt], 0, 0, 0);
    }
    // epilogue: BN + folded per-degree bias + ReLU, predicated bf16 store
    float sc0 = bnscale[f0 + fr],      sh0 = shift2[d * 128 + f0 + fr];
    float sc1 = bnscale[f0 + 16 + fr], sh1 = shift2[d * 128 + f0 + 16 + fr];
    #pragma unroll
    for (int mt = 0; mt < 4; ++mt) {
      #pragma unroll
      for (int j = 0; j < 4; ++j) {
        int n = mt * 16 + rgrp * 4 + j;
        bool w = (n < 60) && (degs[n] == d);
        if (w) {
          float y0 = fmaxf(acc[mt][0][j] * sc0 + sh0, 0.f);
          float y1 = fmaxf(acc[mt][1][j] * sc1 + sh1, 0.f);
          xo[n * 128 + f0 + fr] = f2bf(y0);
          xo[n * 128 + f0 + 16 + fr] = f2bf(y1);
        }
      }
    }
  }
}

// ---------------- Conv1D (implicit GEMM, bf16 MFMA) + BN + ReLU ----------------
__global__ __launch_bounds__(512, 2) void conv_bn(
    const u16* __restrict__ x3, const u16* __restrict__ wct,
    const float* __restrict__ bnscale, const float* __restrict__ bnshift,
    float* __restrict__ out) {
  __shared__ u16 A[4 * 64 * 128];   // 64 KB, 16B-unit XOR-swizzled rows
  const int tid = threadIdx.x;
  const int lane = tid & 63;
  const int wid = __builtin_amdgcn_readfirstlane(tid >> 6);
  const int b0 = blockIdx.x * 4;

  for (int op = wid; op < 64; op += 8) {
    int off = op * 1024 + lane * 16;      // byte offset in A
    int bl = off >> 14;
    int row = (off >> 8) & 63;
    int unit = (off >> 4) & 15;
    int sunit = unit ^ (row & 7);
    int rowc = row < 60 ? row : 59;
    const u16* src = x3 + (((size_t)(b0 + bl) * 60 + rowc) << 7) + sunit * 8;
    __builtin_amdgcn_global_load_lds((as1_void*)src,
                                     (as3_void*)((char*)A + op * 1024), 16, 0, 0);
  }
  __syncthreads();

  const int wr = wid >> 1;   // molecule within block
  const int wc = wid & 1;    // filter half
  f32x4 acc[3][4];
  #pragma unroll
  for (int rt = 0; rt < 3; ++rt)
    #pragma unroll
    for (int ct = 0; ct < 4; ++ct) acc[rt][ct] = (f32x4){0.f, 0.f, 0.f, 0.f};

  for (int ks = 0; ks < 64; ++ks) {
    int rowadd = ks >> 2;
    int unit = ((ks & 3) << 2) + (lane >> 4);
    bf16x8 a[3], bfr[4];
    #pragma unroll
    for (int rt = 0; rt < 3; ++rt) {
      int arow = rt * 16 + (lane & 15) + rowadd;       // <= 62
      int uo = unit ^ (arow & 7);                      // read-side swizzle
      a[rt] = *reinterpret_cast<const bf16x8*>(&A[wr * 8192 + arow * 128 + uo * 8]);
    }
    const u16* wp = wct + ks * 32 + ((lane >> 4) << 3);
    #pragma unroll
    for (int ct = 0; ct < 4; ++ct) {
      int f = (wc * 4 + ct) * 16 + (lane & 15);
      bfr[ct] = *reinterpret_cast<const bf16x8*>(wp + (size_t)f * 2048);
    }
    #pragma unroll
    for (int rt = 0; rt < 3; ++rt)
      #pragma unroll
      for (int ct = 0; ct < 4; ++ct)
        acc[rt][ct] = __builtin_amdgcn_mfma_f32_16x16x32_bf16(a[rt], bfr[ct],
                                                              acc[rt][ct], 0, 0, 0);
  }

  const size_t bb = b0 + wr;
  #pragma unroll
  for (int ct = 0; ct < 4; ++ct) {
    int f = (wc * 4 + ct) * 16 + (lane & 15);
    float sc = bnscale[f], sh = bnshift[f];
    #pragma unroll
    for (int rt = 0; rt < 3; ++rt) {
      #pragma unroll
      for (int j = 0; j < 4; ++j) {
        int t = rt * 16 + ((lane >> 4) << 2) + j;
        if (t < 45) {
          float y = fmaxf(acc[rt][ct][j] * sc + sh, 0.f);
          out[(bb * 45 + t) * 128 + f] = y;
        }
      }
    }
  }
}

extern "C" void kernel_launch(void* const* d_in, const int* in_sizes, int n_in,
                              void* d_out, int out_size, void* d_ws, size_t ws_size,
                              hipStream_t stream) {
  const float* atoms = (const float*)d_in[0];
  const float* bonds = (const float*)d_in[1];
  const int*   edges = (const int*)d_in[2];
  const float* W1 = (const float*)d_in[3]; const float* b1 = (const float*)d_in[4];
  const float* W2 = (const float*)d_in[5]; const float* b2 = (const float*)d_in[6];
  const float* W3 = (const float*)d_in[7]; const float* b3 = (const float*)d_in[8];
  const float* Wc = (const float*)d_in[9];

  char* ws = (char*)d_ws;
  float* scale  = (float*)(ws + OFF_BN);
  float* shift  = scale + 512;
  float* shift2 = (float*)(ws + OFF_SH2);
  u16*   bsum   = (u16*)(ws + OFF_BSUM);
  u16*   wt1    = (u16*)(ws + OFF_WT1);
  u16*   wt2    = (u16*)(ws + OFF_WT2);
  u16*   wt3    = (u16*)(ws + OFF_WT3);
  u16*   wct    = (u16*)(ws + OFF_WCT);
  u16*   x1     = (u16*)(ws + OFF_X1);
  u16*   x3     = (u16*)(ws + OFF_X3);
  u16*   x2     = (u16*)d_out;   // scratch; overwritten by conv afterwards

  bn_prep<<<1, 512, 0, stream>>>(
      (const float*)d_in[10], (const float*)d_in[11], (const float*)d_in[12], (const float*)d_in[13],
      (const float*)d_in[14], (const float*)d_in[15], (const float*)d_in[16], (const float*)d_in[17],
      (const float*)d_in[18], (const float*)d_in[19], (const float*)d_in[20], (const float*)d_in[21],
      (const float*)d_in[22], (const float*)d_in[23], (const float*)d_in[24], (const float*)d_in[25],
      b1, b2, b3, scale, shift, shift2);
  bsum_prep<<<240, 256, 0, stream>>>(bonds, bsum);
  wct_prep<<<64, 512, 0, stream>>>(Wc, wct);
  wt_prep<68, 96><<<(6 * 128 * 96 / 8 + 255) / 256, 256, 0, stream>>>(W1, wt1);
  wt_prep<134, 160><<<(6 * 128 * 160 / 8 + 255) / 256, 256, 0, stream>>>(W2, wt2);
  wt_prep<134, 160><<<(6 * 128 * 160 / 8 + 255) / 256, 256, 0, stream>>>(W3, wt3);

  ngf_mfma<62, 68, 96, false><<<1024, 256, 0, stream>>>(
      atoms, edges, bsum, wt1, scale + 0, shift2 + 0, x1);
  ngf_mfma<128, 134, 160, true><<<1024, 256, 0, stream>>>(
      x1, edges, bsum, wt2, scale + 128, shift2 + 768, x2);
  ngf_mfma<128, 134, 160, true><<<1024, 256, 0, stream>>>(
      x2, edges, bsum, wt3, scale + 256, shift2 + 1536, x3);
  conv_bn<<<256, 512, 0, stream>>>(x3, wct, scale + 384, shift + 384, (float*)d_out);
}

// Round 3
// 261.235 us; speedup vs baseline: 1.8481x; 1.2415x over previous
//
#include <hip/hip_runtime.h>
#include <hip/hip_bf16.h>

typedef __attribute__((ext_vector_type(8))) short bf16x8;
typedef __attribute__((ext_vector_type(4))) short short4v;
typedef __attribute__((ext_vector_type(4))) float f32x4;
typedef unsigned short u16;
typedef const __attribute__((address_space(1))) void as1_void;
typedef __attribute__((address_space(3))) void as3_void;

// dims: B=1024 N=60 D=5 Fa=62 Fb=6 width=128; conv KSZ=16 FILT=128 Tout=45
static constexpr size_t OFF_BN   = 0;                        // scale[4][128]+shift[4][128] = 4096
static constexpr size_t OFF_SH2  = 4096;                     // shift2[3][6][128] f32 = 9216
static constexpr size_t OFF_BSUM = 13312;                    // 61440*6*2 (bf16) = 737280
static constexpr size_t OFF_WT1  = 750592;                   // 6*128*96*2  = 147456
static constexpr size_t OFF_WT2  = 898048;                   // 6*128*160*2 = 245760
static constexpr size_t OFF_WT3  = 1143808;                  // 245760
static constexpr size_t OFF_WCF  = 1389568;                  // 64*8*64*8*2 = 524288
static constexpr size_t OFF_X1   = 1913856;                  // 61440*128*2 = 15728640
static constexpr size_t OFF_X3   = 17642496;                 // 15728640 -> ends 33371136
// x2 lives in d_out (bf16 15.7MB < f32 out 23.6MB; dead before conv writes)

__device__ __forceinline__ float bf2f(u16 r) {
  union { unsigned u; float f; } cv; cv.u = ((unsigned)r) << 16; return cv.f;
}
__device__ __forceinline__ u16 f2bf(float x) {
  __hip_bfloat16 h = __float2bfloat16(x); return *(u16*)&h;
}

// ---------------- prep: BN scale/shift + per-degree folded bias ----------------
__global__ __launch_bounds__(512) void bn_prep(
    const float* g1, const float* be1, const float* m1, const float* v1,
    const float* g2, const float* be2, const float* m2, const float* v2,
    const float* g3, const float* be3, const float* m3, const float* v3,
    const float* g4, const float* be4, const float* m4, const float* v4,
    const float* bb1, const float* bb2, const float* bb3,
    float* __restrict__ scale, float* __restrict__ shift,
    float* __restrict__ shift2) {
  int t = threadIdx.x;                   // 512 threads exactly
  const float* gs[4] = {g1, g2, g3, g4};
  const float* bs[4] = {be1, be2, be3, be4};
  const float* ms[4] = {m1, m2, m3, m4};
  const float* vs[4] = {v1, v2, v3, v4};
  int l = t >> 7, ch = t & 127;
  float g = gs[l][ch], be = bs[l][ch], m = ms[l][ch], v = vs[l][ch];
  float sc = g / sqrtf(v + 1e-3f);       // keras BN epsilon
  scale[t] = sc;
  shift[t] = be - m * sc;
  __syncthreads();
  const float* bl[3] = {bb1, bb2, bb3};
  for (int i = t; i < 3 * 6 * 128; i += 512) {
    int ll = i / 768, r = i % 768, f = r & 127;   // r = d*128+f
    shift2[i] = bl[ll][r] * scale[ll * 128 + f] + shift[ll * 128 + f];
  }
}

// ---------------- prep: bond sums [B*N][6] bf16 ----------------
__global__ __launch_bounds__(256) void bsum_prep(const float* __restrict__ bonds,
                                                 u16* __restrict__ bsum) {
  int a = blockIdx.x * 256 + threadIdx.x;   // 61440 atoms
  const float* p = bonds + (size_t)a * 30;
  float s[6] = {0.f, 0.f, 0.f, 0.f, 0.f, 0.f};
  #pragma unroll
  for (int d = 0; d < 5; ++d)
    #pragma unroll
    for (int j = 0; j < 6; ++j) s[j] += p[d * 6 + j];
  #pragma unroll
  for (int j = 0; j < 6; ++j) bsum[(size_t)a * 6 + j] = f2bf(s[j]);
}

// ------- prep: layer W [6][FIN][128] f32 -> fragment-major wtf -------
// wtf[(((d*KSTEPS+ks)*8 + ftile)*64 + lane)*8 + i] = bf16(W[d][k][f]), k=ks*32+(lane>>4)*8+i,
// f = ftile*16 + (lane&15); zero-padded for k >= FIN.
template <int FIN, int KSTEPS>
__global__ __launch_bounds__(256) void wtf_prep(const float* __restrict__ W,
                                                u16* __restrict__ wtf) {
  int v = blockIdx.x * 256 + threadIdx.x;
  if (v >= 6 * KSTEPS * 8 * 64) return;
  int lane = v & 63;
  int ftile = (v >> 6) & 7;
  int ks = (v >> 9) % KSTEPS;
  int d = (v >> 9) / KSTEPS;
  int f = ftile * 16 + (lane & 15);
  int k0 = ks * 32 + (lane >> 4) * 8;
  bf16x8 o;
  #pragma unroll
  for (int i = 0; i < 8; ++i) {
    int k = k0 + i;
    float x = (k < FIN) ? W[((size_t)d * FIN + k) * 128 + f] : 0.f;
    o[i] = (short)f2bf(x);
  }
  *reinterpret_cast<bf16x8*>(&wtf[(size_t)v * 8]) = o;
}

// ------- prep: Wc [16][128][128] f32 -> fragment-major wcf -------
// wcf[((ks*8 + ftile)*64 + lane)*8 + i] = bf16(Wc[tap][ch][f]); k = ks*32+(lane>>4)*8+i,
// tap = k>>7, ch = k&127, f = ftile*16 + (lane&15).
__global__ __launch_bounds__(512) void wcf_prep(const float* __restrict__ Wc,
                                                u16* __restrict__ wcf) {
  int v = blockIdx.x * 512 + threadIdx.x;   // 32768
  int lane = v & 63;
  int ftile = (v >> 6) & 7;
  int ks = v >> 9;
  int f = ftile * 16 + (lane & 15);
  int k0 = ks * 32 + (lane >> 4) * 8;
  int tap = k0 >> 7, ch0 = k0 & 127;
  bf16x8 o;
  #pragma unroll
  for (int i = 0; i < 8; ++i)
    o[i] = (short)f2bf(Wc[((size_t)tap * 128 + ch0 + i) * 128 + f]);
  *reinterpret_cast<bf16x8*>(&wcf[(size_t)v * 8]) = o;
}

// ---------------- NGF layer: gather + per-degree MFMA GEMM + BN + ReLU ----------------
template <int CIN, int FIN, int KP, bool IN_BF16>
__global__ __launch_bounds__(256, 4) void ngf_mfma(
    const void* __restrict__ xin_g, const int* __restrict__ edges_g,
    const u16* __restrict__ bsum, const u16* __restrict__ wtf,
    const float* __restrict__ bnscale, const float* __restrict__ shift2,
    u16* __restrict__ xout) {
  constexpr int KSTEPS = KP / 32;
  constexpr int CW = (CIN <= 64) ? 64 : 128;
  __shared__ u16 buf0[60 * CIN];            // bf16 input stage
  __shared__ u16 featsb[64 * KP];           // bf16 feats, unit-XOR swizzled
  __shared__ int eds[300];
  __shared__ int degs[64];
  __shared__ int presentS;
  const int b = blockIdx.x, tid = threadIdx.x;
  const int lane = tid & 63;
  const int wid = __builtin_amdgcn_readfirstlane(tid >> 6);

  // phase A: stage edges + x_in (bf16), zero feats
  if (tid == 0) presentS = 0;
  for (int i = tid; i < 300; i += 256) eds[i] = edges_g[b * 300 + i];
  if (IN_BF16) {
    const bf16x8* xg = (const bf16x8*)((const u16*)xin_g + (size_t)b * 60 * CIN);
    bf16x8* dst = (bf16x8*)buf0;
    for (int i = tid; i < 60 * CIN / 8; i += 256) dst[i] = xg[i];
  } else {
    const float4* xg = (const float4*)((const float*)xin_g + (size_t)b * 60 * CIN);
    for (int i = tid; i < 60 * CIN / 4; i += 256) {
      float4 v = xg[i];
      buf0[i * 4 + 0] = f2bf(v.x); buf0[i * 4 + 1] = f2bf(v.y);
      buf0[i * 4 + 2] = f2bf(v.z); buf0[i * 4 + 3] = f2bf(v.w);
    }
  }
  {
    short4v* fz = (short4v*)featsb;
    for (int i = tid; i < 64 * KP / 4; i += 256) fz[i] = (short4v){0, 0, 0, 0};
  }
  __syncthreads();

  // phase B: degrees + presence mask; gather feats (bf16, unit-swizzled)
  if (tid < 64) {
    int dg = 7;
    if (tid < 60) {
      dg = 0;
      #pragma unroll
      for (int d = 0; d < 5; ++d) dg += (eds[tid * 5 + d] >= 0);
      atomicOr(&presentS, 1 << dg);
    }
    degs[tid] = dg;
  }
  for (int i = tid; i < 60 * CW; i += 256) {
    int n = i / CW, c = i % CW;
    if (c < CIN) {
      float v = bf2f(buf0[n * CIN + c]);
      #pragma unroll
      for (int d = 0; d < 5; ++d) {
        int e = eds[n * 5 + d];
        if (e >= 0) v += bf2f(buf0[e * CIN + c]);
      }
      featsb[n * KP + ((((c >> 3) ^ ((n >> 1) & 3)) << 3) | (c & 7))] = f2bf(v);
    }
  }
  for (int i = tid; i < 360; i += 256) {
    int n = i / 6, c = CIN + (i % 6);
    featsb[n * KP + ((((c >> 3) ^ ((n >> 1) & 3)) << 3) | (c & 7))] = bsum[(size_t)b * 360 + i];
  }
  __syncthreads();

  // phase C: per-degree MFMA passes, coalesced fragment-major B + 1-deep prefetch
  const int pres = presentS;
  const int rgrp = lane >> 4;
  const int fr = lane & 15;
  const int f0 = wid * 32;
  u16* xo = xout + (size_t)b * 7680;

  for (int d = 0; d < 6; ++d) {
    if (!(pres & (1 << d))) continue;
    f32x4 acc[4][2];
    #pragma unroll
    for (int mt = 0; mt < 4; ++mt)
      #pragma unroll
      for (int nt = 0; nt < 2; ++nt) acc[mt][nt] = (f32x4){0.f, 0.f, 0.f, 0.f};

    bf16x8 bcur[2], bnxt[2];
    #pragma unroll
    for (int nt = 0; nt < 2; ++nt)
      bcur[nt] = *reinterpret_cast<const bf16x8*>(
          &wtf[((((size_t)d * KSTEPS + 0) * 8 + wid * 2 + nt) * 64 + lane) * 8]);

    #pragma unroll
    for (int ks = 0; ks < KSTEPS; ++ks) {
      if (ks + 1 < KSTEPS) {
        #pragma unroll
        for (int nt = 0; nt < 2; ++nt)
          bnxt[nt] = *reinterpret_cast<const bf16x8*>(
              &wtf[((((size_t)d * KSTEPS + ks + 1) * 8 + wid * 2 + nt) * 64 + lane) * 8]);
      }
      const int k0 = ks * 32 + rgrp * 8;
      bf16x8 a[4];
      #pragma unroll
      for (int mt = 0; mt < 4; ++mt) {
        int r = mt * 16 + fr;
        int u = (k0 >> 3) ^ ((r >> 1) & 3);
        a[mt] = *reinterpret_cast<const bf16x8*>(&featsb[r * KP + u * 8]);
      }
      #pragma unroll
      for (int mt = 0; mt < 4; ++mt)
        #pragma unroll
        for (int nt = 0; nt < 2; ++nt)
          acc[mt][nt] = __builtin_amdgcn_mfma_f32_16x16x32_bf16(a[mt], bcur[nt],
                                                                acc[mt][nt], 0, 0, 0);
      #pragma unroll
      for (int nt = 0; nt < 2; ++nt) bcur[nt] = bnxt[nt];
    }

    float sc0 = bnscale[f0 + fr],      sh0 = shift2[d * 128 + f0 + fr];
    float sc1 = bnscale[f0 + 16 + fr], sh1 = shift2[d * 128 + f0 + 16 + fr];
    #pragma unroll
    for (int mt = 0; mt < 4; ++mt) {
      #pragma unroll
      for (int j = 0; j < 4; ++j) {
        int n = mt * 16 + rgrp * 4 + j;
        bool w = (n < 60) && (degs[n] == d);
        if (w) {
          float y0 = fmaxf(acc[mt][0][j] * sc0 + sh0, 0.f);
          float y1 = fmaxf(acc[mt][1][j] * sc1 + sh1, 0.f);
          xo[n * 128 + f0 + fr] = f2bf(y0);
          xo[n * 128 + f0 + 16 + fr] = f2bf(y1);
        }
      }
    }
  }
}

// ---------------- Conv1D (implicit GEMM, bf16 MFMA) + BN + ReLU ----------------
// 2 molecules/block, 4 waves; A in swizzled LDS (32KB); B fragment-major from
// global (coalesced 1KB bursts, shared across wave pairs via L1) + 1-deep prefetch.
__global__ __launch_bounds__(256, 4) void conv_bn(
    const u16* __restrict__ x3, const u16* __restrict__ wcf,
    const float* __restrict__ bnscale, const float* __restrict__ bnshift,
    float* __restrict__ out) {
  __shared__ u16 A[2 * 64 * 128];   // 32 KB, 16B-unit XOR-swizzled rows
  const int tid = threadIdx.x;
  const int lane = tid & 63;
  const int wid = __builtin_amdgcn_readfirstlane(tid >> 6);
  const int b0 = blockIdx.x * 2;

  for (int op = wid; op < 32; op += 4) {
    int off = op * 1024 + lane * 16;      // byte offset in A
    int bl = off >> 14;                   // molecule 0/1
    int row = (off >> 8) & 63;
    int unit = (off >> 4) & 15;
    int sunit = unit ^ (row & 7);
    int rowc = row < 60 ? row : 59;
    const u16* src = x3 + (((size_t)(b0 + bl) * 60 + rowc) << 7) + sunit * 8;
    __builtin_amdgcn_global_load_lds((as1_void*)src,
                                     (as3_void*)((char*)A + op * 1024), 16, 0, 0);
  }
  __syncthreads();

  const int wr = wid >> 1;   // molecule within block
  const int wc = wid & 1;    // filter half
  f32x4 acc[3][4];
  #pragma unroll
  for (int rt = 0; rt < 3; ++rt)
    #pragma unroll
    for (int ct = 0; ct < 4; ++ct) acc[rt][ct] = (f32x4){0.f, 0.f, 0.f, 0.f};

  bf16x8 bcur[4], bnxt[4];
  #pragma unroll
  for (int ct = 0; ct < 4; ++ct)
    bcur[ct] = *reinterpret_cast<const bf16x8*>(
        &wcf[(((size_t)0 * 8 + wc * 4 + ct) * 64 + lane) * 8]);

  #pragma unroll 4
  for (int ks = 0; ks < 64; ++ks) {
    if (ks < 63) {
      #pragma unroll
      for (int ct = 0; ct < 4; ++ct)
        bnxt[ct] = *reinterpret_cast<const bf16x8*>(
            &wcf[((((size_t)ks + 1) * 8 + wc * 4 + ct) * 64 + lane) * 8]);
    }
    int rowadd = ks >> 2;
    int unit = ((ks & 3) << 2) + (lane >> 4);
    bf16x8 a[3];
    #pragma unroll
    for (int rt = 0; rt < 3; ++rt) {
      int arow = rt * 16 + (lane & 15) + rowadd;       // <= 62
      int uo = unit ^ (arow & 7);                      // read-side swizzle
      a[rt] = *reinterpret_cast<const bf16x8*>(&A[wr * 8192 + arow * 128 + uo * 8]);
    }
    #pragma unroll
    for (int rt = 0; rt < 3; ++rt)
      #pragma unroll
      for (int ct = 0; ct < 4; ++ct)
        acc[rt][ct] = __builtin_amdgcn_mfma_f32_16x16x32_bf16(a[rt], bcur[ct],
                                                              acc[rt][ct], 0, 0, 0);
    #pragma unroll
    for (int ct = 0; ct < 4; ++ct) bcur[ct] = bnxt[ct];
  }

  const size_t bb = b0 + wr;
  #pragma unroll
  for (int ct = 0; ct < 4; ++ct) {
    int f = (wc * 4 + ct) * 16 + (lane & 15);
    float sc = bnscale[f], sh = bnshift[f];
    #pragma unroll
    for (int rt = 0; rt < 3; ++rt) {
      #pragma unroll
      for (int j = 0; j < 4; ++j) {
        int t = rt * 16 + ((lane >> 4) << 2) + j;
        if (t < 45) {
          float y = fmaxf(acc[rt][ct][j] * sc + sh, 0.f);
          out[(bb * 45 + t) * 128 + f] = y;
        }
      }
    }
  }
}

extern "C" void kernel_launch(void* const* d_in, const int* in_sizes, int n_in,
                              void* d_out, int out_size, void* d_ws, size_t ws_size,
                              hipStream_t stream) {
  const float* atoms = (const float*)d_in[0];
  const float* bonds = (const float*)d_in[1];
  const int*   edges = (const int*)d_in[2];
  const float* W1 = (const float*)d_in[3]; const float* b1 = (const float*)d_in[4];
  const float* W2 = (const float*)d_in[5]; const float* b2 = (const float*)d_in[6];
  const float* W3 = (const float*)d_in[7]; const float* b3 = (const float*)d_in[8];
  const float* Wc = (const float*)d_in[9];

  char* ws = (char*)d_ws;
  float* scale  = (float*)(ws + OFF_BN);
  float* shift  = scale + 512;
  float* shift2 = (float*)(ws + OFF_SH2);
  u16*   bsum   = (u16*)(ws + OFF_BSUM);
  u16*   wt1    = (u16*)(ws + OFF_WT1);
  u16*   wt2    = (u16*)(ws + OFF_WT2);
  u16*   wt3    = (u16*)(ws + OFF_WT3);
  u16*   wcf    = (u16*)(ws + OFF_WCF);
  u16*   x1     = (u16*)(ws + OFF_X1);
  u16*   x3     = (u16*)(ws + OFF_X3);
  u16*   x2     = (u16*)d_out;   // scratch; overwritten by conv afterwards

  bn_prep<<<1, 512, 0, stream>>>(
      (const float*)d_in[10], (const float*)d_in[11], (const float*)d_in[12], (const float*)d_in[13],
      (const float*)d_in[14], (const float*)d_in[15], (const float*)d_in[16], (const float*)d_in[17],
      (const float*)d_in[18], (const float*)d_in[19], (const float*)d_in[20], (const float*)d_in[21],
      (const float*)d_in[22], (const float*)d_in[23], (const float*)d_in[24], (const float*)d_in[25],
      b1, b2, b3, scale, shift, shift2);
  bsum_prep<<<240, 256, 0, stream>>>(bonds, bsum);
  wcf_prep<<<64, 512, 0, stream>>>(Wc, wcf);
  wtf_prep<68, 3><<<(6 * 3 * 8 * 64 + 255) / 256, 256, 0, stream>>>(W1, wt1);
  wtf_prep<134, 5><<<(6 * 5 * 8 * 64 + 255) / 256, 256, 0, stream>>>(W2, wt2);
  wtf_prep<134, 5><<<(6 * 5 * 8 * 64 + 255) / 256, 256, 0, stream>>>(W3, wt3);

  ngf_mfma<62, 68, 96, false><<<1024, 256, 0, stream>>>(
      atoms, edges, bsum, wt1, scale + 0, shift2 + 0, x1);
  ngf_mfma<128, 134, 160, true><<<1024, 256, 0, stream>>>(
      x1, edges, bsum, wt2, scale + 128, shift2 + 768, x2);
  ngf_mfma<128, 134, 160, true><<<1024, 256, 0, stream>>>(
      x2, edges, bsum, wt3, scale + 256, shift2 + 1536, x3);
  conv_bn<<<512, 256, 0, stream>>>(x3, wcf, scale + 384, shift + 384, (float*)d_out);
}

// Round 4
// 218.598 us; speedup vs baseline: 2.2085x; 1.1950x over previous
//
#include <hip/hip_runtime.h>
#include <hip/hip_bf16.h>

typedef __attribute__((ext_vector_type(8))) short bf16x8;
typedef __attribute__((ext_vector_type(4))) short short4v;
typedef __attribute__((ext_vector_type(4))) float f32x4;
typedef unsigned short u16;

// dims: B=1024 N=60 D=5 Fa=62 Fb=6 width=128; conv KSZ=16 FILT=128 Tout=45
static constexpr size_t OFF_BN   = 0;         // scale[4][128]+shift[4][128] = 4096
static constexpr size_t OFF_SH2  = 4096;      // shift2[3][6][128] f32 = 9216
static constexpr size_t OFF_BSUM = 13312;     // 61440*6*2 (bf16) = 737280
static constexpr size_t OFF_WT1  = 750592;    // 6*3*8*64*8*2 = 147456
static constexpr size_t OFF_WT2  = 898048;    // 6*5*8*64*8*2 = 245760
static constexpr size_t OFF_WT3  = 1143808;   // 245760
static constexpr size_t OFF_WCF  = 1389568;   // 64*8*64*8*2 = 524288 -> ends 1913856 (~1.9MB)

__device__ __forceinline__ float bf2f(u16 r) {
  union { unsigned u; float f; } cv; cv.u = ((unsigned)r) << 16; return cv.f;
}
__device__ __forceinline__ u16 f2bf(float x) {
  __hip_bfloat16 h = __float2bfloat16(x); return *(u16*)&h;
}
// x-buffer layout: conv-compatible unit swizzle (16B unit XOR row&7)
__device__ __forceinline__ int xswz(int n, int c) {
  return n * 128 + ((((c >> 3) ^ (n & 7)) << 3) | (c & 7));
}
// feats layout: stride 160, unit XOR (row>>1)&3 (R3-proven for GEMM A-frags)
__device__ __forceinline__ int fswz(int n, int c) {
  return n * 160 + ((((c >> 3) ^ ((n >> 1) & 3)) << 3) | (c & 7));
}

// ---------------- prep: BN scale/shift + per-degree folded bias (7 blocks) ----------------
__global__ __launch_bounds__(512) void bn_prep(
    const float* g1, const float* be1, const float* m1, const float* v1,
    const float* g2, const float* be2, const float* m2, const float* v2,
    const float* g3, const float* be3, const float* m3, const float* v3,
    const float* g4, const float* be4, const float* m4, const float* v4,
    const float* bb1, const float* bb2, const float* bb3,
    float* __restrict__ scale, float* __restrict__ shift,
    float* __restrict__ shift2) {
  int bid = blockIdx.x, t = threadIdx.x;
  if (bid == 0) {
    const float* gs[4] = {g1, g2, g3, g4};
    const float* bs[4] = {be1, be2, be3, be4};
    const float* ms[4] = {m1, m2, m3, m4};
    const float* vs[4] = {v1, v2, v3, v4};
    int l = t >> 7, ch = t & 127;
    float g = gs[l][ch], be = bs[l][ch], m = ms[l][ch], v = vs[l][ch];
    float sc = g / sqrtf(v + 1e-3f);       // keras BN epsilon
    scale[t] = sc;
    shift[t] = be - m * sc;
  } else if (t < 384) {
    int d = bid - 1;                       // 0..5
    const float* gs[3] = {g1, g2, g3};
    const float* bs[3] = {be1, be2, be3};
    const float* ms[3] = {m1, m2, m3};
    const float* vs[3] = {v1, v2, v3};
    const float* bl[3] = {bb1, bb2, bb3};
    int ll = t >> 7, f = t & 127;
    float g = gs[ll][f], be = bs[ll][f], m = ms[ll][f], v = vs[ll][f];
    float sc = g / sqrtf(v + 1e-3f);
    float sh = be - m * sc;
    shift2[ll * 768 + d * 128 + f] = bl[ll][d * 128 + f] * sc + sh;
  }
}

// ---------------- prep: bond sums [B*N][6] bf16 ----------------
__global__ __launch_bounds__(256) void bsum_prep(const float* __restrict__ bonds,
                                                 u16* __restrict__ bsum) {
  int a = blockIdx.x * 256 + threadIdx.x;   // 61440 atoms
  const float* p = bonds + (size_t)a * 30;
  float s[6] = {0.f, 0.f, 0.f, 0.f, 0.f, 0.f};
  #pragma unroll
  for (int d = 0; d < 5; ++d)
    #pragma unroll
    for (int j = 0; j < 6; ++j) s[j] += p[d * 6 + j];
  #pragma unroll
  for (int j = 0; j < 6; ++j) bsum[(size_t)a * 6 + j] = f2bf(s[j]);
}

// ------- prep: layer W [6][FIN][128] f32 -> fragment-major wtf -------
template <int FIN, int KSTEPS>
__global__ __launch_bounds__(256) void wtf_prep(const float* __restrict__ W,
                                                u16* __restrict__ wtf) {
  int v = blockIdx.x * 256 + threadIdx.x;
  if (v >= 6 * KSTEPS * 8 * 64) return;
  int lane = v & 63;
  int ftile = (v >> 6) & 7;
  int ks = (v >> 9) % KSTEPS;
  int d = (v >> 9) / KSTEPS;
  int f = ftile * 16 + (lane & 15);
  int k0 = ks * 32 + (lane >> 4) * 8;
  bf16x8 o;
  #pragma unroll
  for (int i = 0; i < 8; ++i) {
    int k = k0 + i;
    float x = (k < FIN) ? W[((size_t)d * FIN + k) * 128 + f] : 0.f;
    o[i] = (short)f2bf(x);
  }
  *reinterpret_cast<bf16x8*>(&wtf[(size_t)v * 8]) = o;
}

// ------- prep: Wc [16][128][128] f32 -> fragment-major wcf -------
__global__ __launch_bounds__(512) void wcf_prep(const float* __restrict__ Wc,
                                                u16* __restrict__ wcf) {
  int v = blockIdx.x * 512 + threadIdx.x;   // 32768
  int lane = v & 63;
  int ftile = (v >> 6) & 7;
  int ks = v >> 9;
  int f = ftile * 16 + (lane & 15);
  int k0 = ks * 32 + (lane >> 4) * 8;
  int tap = k0 >> 7, ch0 = k0 & 127;
  bf16x8 o;
  #pragma unroll
  for (int i = 0; i < 8; ++i)
    o[i] = (short)f2bf(Wc[((size_t)tap * 128 + ch0 + i) * 128 + f]);
  *reinterpret_cast<bf16x8*>(&wcf[(size_t)v * 8]) = o;
}

// ---------------- NGF layer device body: gather + per-degree GEMM + BN + ReLU ----------------
template <int CIN, int KSTEPS>
__device__ __forceinline__ void ngf_layer_dev(
    u16* __restrict__ xb, u16* __restrict__ feats,
    const int* __restrict__ eds, const int* __restrict__ degs,
    const int* __restrict__ presentS,
    const u16* __restrict__ bsum_b,                    // this molecule's bond sums
    const u16* __restrict__ wtf,                       // layer weights, fragment-major
    const float* __restrict__ sc_l, const float* __restrict__ sh2_l,
    int tid, int lane, int wid) {
  constexpr int CW = (CIN <= 64) ? 64 : 128;
  // ---- gather: feats[n][c] = x[n][c] + sum_e x[e][c] ; bond-sum cols ----
  for (int i = tid; i < 60 * CW; i += 256) {
    int n = i / CW, c = i % CW;      // CW pow2 -> shifts; n wave-uniform
    if (c < CIN) {
      float v = bf2f(xb[xswz(n, c)]);
      #pragma unroll
      for (int d = 0; d < 5; ++d) {
        int e = eds[n * 5 + d];
        if (e >= 0) v += bf2f(xb[xswz(e, c)]);
      }
      feats[fswz(n, c)] = f2bf(v);
    }
  }
  for (int i = tid; i < 360; i += 256) {
    int n = i / 6, c = CIN + (i % 6);
    feats[fswz(n, c)] = bsum_b[i];
  }
  __syncthreads();   // feats ready; also guards xb reads before epilogue writes

  // ---- per-degree MFMA GEMM: wave owns filters f0..f0+31, all 60 M rows ----
  const int pres = *presentS;
  const int rgrp = lane >> 4;
  const int fr = lane & 15;
  const int f0 = wid * 32;

  for (int d = 0; d < 6; ++d) {
    if (!(pres & (1 << d))) continue;
    f32x4 acc[4][2];
    #pragma unroll
    for (int mt = 0; mt < 4; ++mt)
      #pragma unroll
      for (int nt = 0; nt < 2; ++nt) acc[mt][nt] = (f32x4){0.f, 0.f, 0.f, 0.f};
    const u16* __restrict__ wd = wtf + (size_t)d * KSTEPS * 4096;
    bf16x8 bcur[2], bnxt[2];
    #pragma unroll
    for (int nt = 0; nt < 2; ++nt)
      bcur[nt] = *reinterpret_cast<const bf16x8*>(
          &wd[(((size_t)0 * 8 + wid * 2 + nt) * 64 + lane) * 8]);
    #pragma unroll
    for (int ks = 0; ks < KSTEPS; ++ks) {
      if (ks + 1 < KSTEPS) {
        #pragma unroll
        for (int nt = 0; nt < 2; ++nt)
          bnxt[nt] = *reinterpret_cast<const bf16x8*>(
              &wd[((((size_t)ks + 1) * 8 + wid * 2 + nt) * 64 + lane) * 8]);
      }
      bf16x8 a[4];
      #pragma unroll
      for (int mt = 0; mt < 4; ++mt) {
        int r = mt * 16 + fr;
        int u = (ks * 4 + rgrp) ^ ((fr >> 1) & 3);
        a[mt] = *reinterpret_cast<const bf16x8*>(&feats[r * 160 + u * 8]);
      }
      #pragma unroll
      for (int mt = 0; mt < 4; ++mt)
        #pragma unroll
        for (int nt = 0; nt < 2; ++nt)
          acc[mt][nt] = __builtin_amdgcn_mfma_f32_16x16x32_bf16(a[mt], bcur[nt],
                                                                acc[mt][nt], 0, 0, 0);
      #pragma unroll
      for (int nt = 0; nt < 2; ++nt) bcur[nt] = bnxt[nt];
    }
    // epilogue: BN + folded per-degree bias + ReLU -> xb (swizzled), predicated
    float s0 = sc_l[f0 + fr],      h0 = sh2_l[d * 128 + f0 + fr];
    float s1 = sc_l[f0 + 16 + fr], h1 = sh2_l[d * 128 + f0 + 16 + fr];
    #pragma unroll
    for (int mt = 0; mt < 4; ++mt) {
      #pragma unroll
      for (int j = 0; j < 4; ++j) {
        int n = mt * 16 + rgrp * 4 + j;
        if (n < 60 && degs[n] == d) {
          xb[xswz(n, f0 + fr)]      = f2bf(fmaxf(acc[mt][0][j] * s0 + h0, 0.f));
          xb[xswz(n, f0 + 16 + fr)] = f2bf(fmaxf(acc[mt][1][j] * s1 + h1, 0.f));
        }
      }
    }
  }
  __syncthreads();   // x_{l+1} complete before next gather / conv
}

// ---------------- MEGA: 1 block = 1 molecule; 3 NGF layers + Conv1D + BN + ReLU ----------------
__global__ __launch_bounds__(256, 4) void mega(
    const float* __restrict__ atoms, const int* __restrict__ edges_g,
    const u16* __restrict__ bsum, const u16* __restrict__ wt1,
    const u16* __restrict__ wt2, const u16* __restrict__ wt3,
    const u16* __restrict__ wcf, const float* __restrict__ scale,
    const float* __restrict__ shift, const float* __restrict__ shift2,
    float* __restrict__ out) {
  __shared__ u16 xb[64 * 128];      // 16 KB  current x (bf16, unit-swizzled)
  __shared__ u16 feats[64 * 160];   // 20 KB  gathered feats (bf16, swizzled)
  __shared__ int eds[300];
  __shared__ int degs[64];
  __shared__ int presentS;
  const int b = blockIdx.x, tid = threadIdx.x;
  const int lane = tid & 63;
  const int wid = __builtin_amdgcn_readfirstlane(tid >> 6);

  // ---- init: edges, atoms->xb (bf16 swizzled), zero feats (pads stay 0 forever) ----
  if (tid == 0) presentS = 0;
  for (int i = tid; i < 300; i += 256) eds[i] = edges_g[b * 300 + i];
  {
    short4v* fz = (short4v*)feats;
    for (int i = tid; i < 64 * 160 / 4; i += 256) fz[i] = (short4v){0, 0, 0, 0};
  }
  for (int i = tid; i < 60 * 64; i += 256) {
    int n = i >> 6, c = i & 63;
    if (c < 62) xb[xswz(n, c)] = f2bf(atoms[(size_t)b * 3720 + n * 62 + c]);
  }
  __syncthreads();

  // degrees + presence (wave 0) runs concurrent with layer-1 gather
  if (tid < 64) {
    int dg = 7;
    if (tid < 60) {
      dg = 0;
      #pragma unroll
      for (int d = 0; d < 5; ++d) dg += (eds[tid * 5 + d] >= 0);
      atomicOr(&presentS, 1 << dg);
    }
    degs[tid] = dg;
  }

  const u16* bsum_b = bsum + (size_t)b * 360;
  ngf_layer_dev<62, 3>(xb, feats, eds, degs, &presentS, bsum_b, wt1,
                       scale + 0, shift2 + 0, tid, lane, wid);
  ngf_layer_dev<128, 5>(xb, feats, eds, degs, &presentS, bsum_b, wt2,
                        scale + 128, shift2 + 768, tid, lane, wid);
  ngf_layer_dev<128, 5>(xb, feats, eds, degs, &presentS, bsum_b, wt3,
                        scale + 256, shift2 + 1536, tid, lane, wid);

  // ---- conv: implicit GEMM over x3 (in xb), 2-deep A/B register rings ----
  {
    const int fr = lane & 15;
    const int rgrp = lane >> 4;
    const int f0 = wid * 32;
    f32x4 cacc[3][2];
    #pragma unroll
    for (int rt = 0; rt < 3; ++rt)
      #pragma unroll
      for (int ct = 0; ct < 2; ++ct) cacc[rt][ct] = (f32x4){0.f, 0.f, 0.f, 0.f};

    bf16x8 br[2][2], ar[2][3];
    auto loadB = [&](int ks, int slot) {
      #pragma unroll
      for (int nt = 0; nt < 2; ++nt)
        br[slot][nt] = *reinterpret_cast<const bf16x8*>(
            &wcf[(((size_t)ks * 8 + wid * 2 + nt) * 64 + lane) * 8]);
    };
    auto loadA = [&](int ks, int slot) {
      int rowadd = ks >> 2;
      int unit = ((ks & 3) << 2) + rgrp;
      #pragma unroll
      for (int rt = 0; rt < 3; ++rt) {
        int arow = rt * 16 + fr + rowadd;          // <= 62 (rows>=60 garbage, discarded)
        int uo = unit ^ (arow & 7);
        ar[slot][rt] = *reinterpret_cast<const bf16x8*>(&xb[arow * 128 + uo * 8]);
      }
    };
    loadB(0, 0); loadB(1, 1); loadA(0, 0);
    #pragma unroll 2
    for (int ks = 0; ks < 64; ++ks) {
      if (ks < 63) loadA(ks + 1, (ks + 1) & 1);
      #pragma unroll
      for (int rt = 0; rt < 3; ++rt)
        #pragma unroll
        for (int ct = 0; ct < 2; ++ct)
          cacc[rt][ct] = __builtin_amdgcn_mfma_f32_16x16x32_bf16(
              ar[ks & 1][rt], br[ks & 1][ct], cacc[rt][ct], 0, 0, 0);
      if (ks < 62) loadB(ks + 2, ks & 1);
    }

    // epilogue: BN4 + ReLU, f32 store. D layout: col=lane&15, row=(lane>>4)*4+j
    #pragma unroll
    for (int ct = 0; ct < 2; ++ct) {
      int f = f0 + ct * 16 + fr;
      float sc = scale[384 + f], sh = shift[384 + f];
      #pragma unroll
      for (int rt = 0; rt < 3; ++rt) {
        #pragma unroll
        for (int j = 0; j < 4; ++j) {
          int t = rt * 16 + rgrp * 4 + j;
          if (t < 45) {
            float y = fmaxf(cacc[rt][ct][j] * sc + sh, 0.f);
            out[((size_t)b * 45 + t) * 128 + f] = y;
          }
        }
      }
    }
  }
}

extern "C" void kernel_launch(void* const* d_in, const int* in_sizes, int n_in,
                              void* d_out, int out_size, void* d_ws, size_t ws_size,
                              hipStream_t stream) {
  const float* atoms = (const float*)d_in[0];
  const float* bonds = (const float*)d_in[1];
  const int*   edges = (const int*)d_in[2];
  const float* W1 = (const float*)d_in[3]; const float* b1 = (const float*)d_in[4];
  const float* W2 = (const float*)d_in[5]; const float* b2 = (const float*)d_in[6];
  const float* W3 = (const float*)d_in[7]; const float* b3 = (const float*)d_in[8];
  const float* Wc = (const float*)d_in[9];

  char* ws = (char*)d_ws;
  float* scale  = (float*)(ws + OFF_BN);
  float* shift  = scale + 512;
  float* shift2 = (float*)(ws + OFF_SH2);
  u16*   bsum   = (u16*)(ws + OFF_BSUM);
  u16*   wt1    = (u16*)(ws + OFF_WT1);
  u16*   wt2    = (u16*)(ws + OFF_WT2);
  u16*   wt3    = (u16*)(ws + OFF_WT3);
  u16*   wcf    = (u16*)(ws + OFF_WCF);

  bn_prep<<<7, 512, 0, stream>>>(
      (const float*)d_in[10], (const float*)d_in[11], (const float*)d_in[12], (const float*)d_in[13],
      (const float*)d_in[14], (const float*)d_in[15], (const float*)d_in[16], (const float*)d_in[17],
      (const float*)d_in[18], (const float*)d_in[19], (const float*)d_in[20], (const float*)d_in[21],
      (const float*)d_in[22], (const float*)d_in[23], (const float*)d_in[24], (const float*)d_in[25],
      b1, b2, b3, scale, shift, shift2);
  bsum_prep<<<240, 256, 0, stream>>>(bonds, bsum);
  wcf_prep<<<64, 512, 0, stream>>>(Wc, wcf);
  wtf_prep<68, 3><<<36, 256, 0, stream>>>(W1, wt1);
  wtf_prep<134, 5><<<60, 256, 0, stream>>>(W2, wt2);
  wtf_prep<134, 5><<<60, 256, 0, stream>>>(W3, wt3);

  mega<<<1024, 256, 0, stream>>>(atoms, edges, bsum, wt1, wt2, wt3, wcf,
                                 scale, shift, shift2, (float*)d_out);
}

// Round 5
// 215.866 us; speedup vs baseline: 2.2365x; 1.0127x over previous
//
#include <hip/hip_runtime.h>
#include <hip/hip_bf16.h>

typedef __attribute__((ext_vector_type(8))) short bf16x8;
typedef __attribute__((ext_vector_type(4))) short short4v;
typedef __attribute__((ext_vector_type(4))) float f32x4;
typedef unsigned short u16;
typedef unsigned char u8;

// dims: B=1024 N=60 D=5 Fa=62 Fb=6 width=128; conv KSZ=16 FILT=128 Tout=45
static constexpr size_t OFF_BN   = 0;        // scale[4][128]+shift[4][128] = 4096
static constexpr size_t OFF_SH2  = 4096;     // shift2[3][6][128] f32 = 9216
static constexpr size_t OFF_BSUM = 13312;    // 61440*6*2 = 737280
static constexpr size_t OFF_WT1  = 750592;   // 6*3*8*64*8*2 = 147456
static constexpr size_t OFF_WT2  = 898048;   // 6*5*8*64*8*2 = 245760
static constexpr size_t OFF_WT3  = 1143808;  // 245760
static constexpr size_t OFF_WCF  = 1389568;  // 64*8*64*8*2 = 524288 -> ends 1913856

__device__ __forceinline__ float bf2f(u16 r) {
  union { unsigned u; float f; } cv; cv.u = ((unsigned)r) << 16; return cv.f;
}
__device__ __forceinline__ u16 f2bf(float x) {
  __hip_bfloat16 h = __float2bfloat16(x); return *(u16*)&h;
}
// xbt (transposed x) layout: [c][n] with 8-n-unit XOR swizzle -> u16 index
__device__ __forceinline__ int xts(int c, int n) {
  return c * 64 + (((n >> 3) ^ (c & 7)) << 3) + (n & 7);
}

// ---------------- merged prep kernel ----------------
__device__ __forceinline__ void emit_wt(u16* dst, const float* W, int FIN, int FIN_A,
                                        int CB, int KSTEPS, int v) {
  int lane = v & 63;
  int ftile = (v >> 6) & 7;
  int ks = (v >> 9) % KSTEPS;
  int d = (v >> 9) / KSTEPS;
  int f = ftile * 16 + (lane & 15);
  int k0 = ks * 32 + (lane >> 4) * 8;
  bf16x8 o;
  #pragma unroll
  for (int i = 0; i < 8; ++i) {
    int k = k0 + i;
    int src = (k < FIN_A) ? k : (k >= CB && k < CB + 6) ? (FIN_A + k - CB) : -1;
    float x = (src >= 0) ? W[((size_t)d * FIN + src) * 128 + f] : 0.f;
    o[i] = (short)f2bf(x);
  }
  *reinterpret_cast<bf16x8*>(&dst[(size_t)v * 8]) = o;
}

__global__ __launch_bounds__(256) void prep(
    const float* __restrict__ bonds, const float* __restrict__ Wc,
    const float* __restrict__ W1, const float* __restrict__ W2, const float* __restrict__ W3,
    const float* g1, const float* be1, const float* m1, const float* v1,
    const float* g2, const float* be2, const float* m2, const float* v2,
    const float* g3, const float* be3, const float* m3, const float* v3,
    const float* g4, const float* be4, const float* m4, const float* v4,
    const float* bb1, const float* bb2, const float* bb3,
    float* __restrict__ scale, float* __restrict__ shift, float* __restrict__ shift2,
    u16* __restrict__ bsum, u16* __restrict__ wt1, u16* __restrict__ wt2,
    u16* __restrict__ wt3, u16* __restrict__ wcf) {
  __shared__ float sb[3840];
  const int b = blockIdx.x, tid = threadIdx.x;
  if (b < 480) {                       // bond sums, 128 atoms/block, coalesced via LDS
    const int base = b * 128;
    const float4* src = (const float4*)(bonds + (size_t)base * 30);
    for (int i = tid; i < 960; i += 256) ((float4*)sb)[i] = src[i];
    __syncthreads();
    if (tid < 128) {
      float s[6] = {0.f, 0.f, 0.f, 0.f, 0.f, 0.f};
      #pragma unroll
      for (int d = 0; d < 5; ++d)
        #pragma unroll
        for (int j = 0; j < 6; ++j) s[j] += sb[tid * 30 + d * 6 + j];
      #pragma unroll
      for (int j = 0; j < 6; ++j) bsum[(size_t)(base + tid) * 6 + j] = f2bf(s[j]);
    }
  } else if (b < 608) {                // wcf: Wc [16][128][128] -> fragment-major
    int v = (b - 480) * 256 + tid;
    int lane = v & 63, ftile = (v >> 6) & 7, ks = v >> 9;
    int f = ftile * 16 + (lane & 15);
    int k0 = ks * 32 + (lane >> 4) * 8;
    int tap = k0 >> 7, ch0 = k0 & 127;
    bf16x8 o;
    #pragma unroll
    for (int i = 0; i < 8; ++i)
      o[i] = (short)f2bf(Wc[((size_t)tap * 128 + ch0 + i) * 128 + f]);
    *reinterpret_cast<bf16x8*>(&wcf[(size_t)v * 8]) = o;
  } else if (b < 644) {                // wt1 (FIN_A=62, bonds at col 64, KSTEPS=3)
    emit_wt(wt1, W1, 68, 62, 64, 3, (b - 608) * 256 + tid);
  } else if (b < 704) {                // wt2
    emit_wt(wt2, W2, 134, 128, 128, 5, (b - 644) * 256 + tid);
  } else if (b < 764) {                // wt3
    emit_wt(wt3, W3, 134, 128, 128, 5, (b - 704) * 256 + tid);
  } else if (b < 766) {                // BN scale/shift (4 layers x 128)
    int idx = (b - 764) * 256 + tid;   // < 512
    const float* gs[4] = {g1, g2, g3, g4};
    const float* bs[4] = {be1, be2, be3, be4};
    const float* ms[4] = {m1, m2, m3, m4};
    const float* vs[4] = {v1, v2, v3, v4};
    int l = idx >> 7, ch = idx & 127;
    float sc = gs[l][ch] / sqrtf(vs[l][ch] + 1e-3f);   // keras BN epsilon
    scale[idx] = sc;
    shift[idx] = bs[l][ch] - ms[l][ch] * sc;
  } else {                             // shift2[3][6][128] = b*scale + shift (folded bias)
    int i = (b - 766) * 256 + tid;
    if (i < 2304) {
      const float* G[3] = {g1, g2, g3};
      const float* Be[3] = {be1, be2, be3};
      const float* M[3] = {m1, m2, m3};
      const float* V[3] = {v1, v2, v3};
      const float* Bl[3] = {bb1, bb2, bb3};
      int ll = i / 768, r = i % 768, f = r & 127;
      float sc = G[ll][f] / sqrtf(V[ll][f] + 1e-3f);
      float sh = Be[ll][f] - M[ll][f] * sc;
      shift2[i] = Bl[ll][r] * sc + sh;
    }
  }
}

// ---------------- per-layer body: MFMA gather + per-degree MFMA GEMM ----------------
// feats layout: [60][160] u16, unit swizzle u' = (u<16) ? u^(n&7) : u
// MPW: gather c-tiles per wave (1 for CIN=64-region, 2 for 128). CB: bond col base.
template <int MPW, int CB, int KSTEPS, bool TOCONV>
__device__ __forceinline__ void layer(
    u16* __restrict__ feats, u16* __restrict__ xbt,
    const u8* __restrict__ S8, const u8* __restrict__ degs8,
    const int* __restrict__ presentS, const u16* __restrict__ bsum_b,
    const u16* __restrict__ wtf, const float* __restrict__ sc_l,
    const float* __restrict__ sh2_l, int tid, int lane, int wid) {
  const int fr = lane & 15, rg = lane >> 4;

  // ---- S fragments: u8 -> bf16, kept in regs for this layer ----
  bf16x8 sf[4][2];
  #pragma unroll
  for (int nt = 0; nt < 4; ++nt) {
    #pragma unroll
    for (int ks = 0; ks < 2; ++ks) {
      int n = nt * 16 + fr, m0 = ks * 32 + rg * 8;
      const unsigned* wp = (const unsigned*)(S8 + n * 64 + m0);
      unsigned lo = wp[0], hi = wp[1];
      bf16x8 v;
      #pragma unroll
      for (int i = 0; i < 4; ++i) v[i] = (short)f2bf((float)((lo >> (i * 8)) & 255u));
      #pragma unroll
      for (int i = 0; i < 4; ++i) v[4 + i] = (short)f2bf((float)((hi >> (i * 8)) & 255u));
      sf[nt][ks] = v;
    }
  }

  // ---- gather GEMM: D^T[c][n] = (x^T)(S^T); A = xbt rows, B = S rows ----
  f32x4 gacc[MPW][4];
  #pragma unroll
  for (int mt = 0; mt < MPW; ++mt)
    #pragma unroll
    for (int nt = 0; nt < 4; ++nt) gacc[mt][nt] = (f32x4){0.f, 0.f, 0.f, 0.f};
  #pragma unroll
  for (int mt = 0; mt < MPW; ++mt) {
    const int c = (wid * MPW + mt) * 16 + fr;
    #pragma unroll
    for (int ks = 0; ks < 2; ++ks) {
      const int m0 = ks * 32 + rg * 8;
      bf16x8 a = *reinterpret_cast<const bf16x8*>(
          &xbt[c * 64 + (((m0 >> 3) ^ (c & 7)) << 3)]);
      #pragma unroll
      for (int nt = 0; nt < 4; ++nt)
        gacc[mt][nt] = __builtin_amdgcn_mfma_f32_16x16x32_bf16(a, sf[nt][ks],
                                                               gacc[mt][nt], 0, 0, 0);
    }
  }
  // write feats (b64 swizzled, predicated n<60)
  #pragma unroll
  for (int mt = 0; mt < MPW; ++mt) {
    const int c0 = (wid * MPW + mt) * 16 + rg * 4;  // mod 8 in {0,4}
    const int uu = c0 >> 3;                          // < 16
    #pragma unroll
    for (int nt = 0; nt < 4; ++nt) {
      const int n = nt * 16 + fr;
      if (n < 60) {
        short4v p;
        #pragma unroll
        for (int j = 0; j < 4; ++j) p[j] = (short)f2bf(gacc[mt][nt][j]);
        *reinterpret_cast<short4v*>(
            &feats[n * 160 + ((uu ^ (n & 7)) << 3) + (c0 & 7)]) = p;
      }
    }
  }
  // bond-sum columns
  for (int i = tid; i < 360; i += 256) {
    int n = i / 6, c = CB + (i % 6);
    int u = c >> 3;
    int uu2 = (u < 16) ? (u ^ (n & 7)) : u;
    feats[n * 160 + (uu2 << 3) + (c & 7)] = bsum_b[i];
  }
  __syncthreads();

  // ---- main GEMM per present degree: OUT^T[f][n]; A = wtf frags, B = feats rows ----
  const int pres = *presentS;
  int dg[4];
  #pragma unroll
  for (int nt = 0; nt < 4; ++nt) dg[nt] = degs8[nt * 16 + fr];
  float4 scv[2];
  #pragma unroll
  for (int mt = 0; mt < 2; ++mt)
    scv[mt] = *reinterpret_cast<const float4*>(&sc_l[(wid * 2 + mt) * 16 + rg * 4]);

  for (int d = 0; d < 6; ++d) {
    if (!(pres & (1 << d))) continue;
    f32x4 acc[2][4];
    #pragma unroll
    for (int mt = 0; mt < 2; ++mt)
      #pragma unroll
      for (int nt = 0; nt < 4; ++nt) acc[mt][nt] = (f32x4){0.f, 0.f, 0.f, 0.f};
    const u16* __restrict__ wd = wtf + (size_t)d * KSTEPS * 4096;
    bf16x8 acur[2], anxt[2];
    #pragma unroll
    for (int mt = 0; mt < 2; ++mt)
      acur[mt] = *reinterpret_cast<const bf16x8*>(
          &wd[((0 * 8 + wid * 2 + mt) * 64 + lane) * 8]);
    #pragma unroll
    for (int ks = 0; ks < KSTEPS; ++ks) {
      if (ks + 1 < KSTEPS) {
        #pragma unroll
        for (int mt = 0; mt < 2; ++mt)
          anxt[mt] = *reinterpret_cast<const bf16x8*>(
              &wd[(((ks + 1) * 8 + wid * 2 + mt) * 64 + lane) * 8]);
      }
      bf16x8 bfr[4];
      const int u = (ks * 32 + rg * 8) >> 3;
      #pragma unroll
      for (int nt = 0; nt < 4; ++nt) {
        const int n = nt * 16 + fr;
        const int uu2 = (u < 16) ? (u ^ (n & 7)) : u;
        bfr[nt] = *reinterpret_cast<const bf16x8*>(&feats[n * 160 + (uu2 << 3)]);
      }
      #pragma unroll
      for (int mt = 0; mt < 2; ++mt)
        #pragma unroll
        for (int nt = 0; nt < 4; ++nt)
          acc[mt][nt] = __builtin_amdgcn_mfma_f32_16x16x32_bf16(acur[mt], bfr[nt],
                                                                acc[mt][nt], 0, 0, 0);
      #pragma unroll
      for (int mt = 0; mt < 2; ++mt) acur[mt] = anxt[mt];
    }
    // epilogue: BN + folded bias + ReLU; write next-x (xbt layout) or conv layout
    #pragma unroll
    for (int mt = 0; mt < 2; ++mt) {
      const int f0 = (wid * 2 + mt) * 16 + rg * 4;   // mod 8 in {0,4}
      float4 shv = *reinterpret_cast<const float4*>(&sh2_l[d * 128 + f0]);
      #pragma unroll
      for (int nt = 0; nt < 4; ++nt) {
        const int n = nt * 16 + fr;
        if (n < 60 && dg[nt] == d) {
          float y0 = fmaxf(acc[mt][nt][0] * scv[mt].x + shv.x, 0.f);
          float y1 = fmaxf(acc[mt][nt][1] * scv[mt].y + shv.y, 0.f);
          float y2 = fmaxf(acc[mt][nt][2] * scv[mt].z + shv.z, 0.f);
          float y3 = fmaxf(acc[mt][nt][3] * scv[mt].w + shv.w, 0.f);
          if (TOCONV) {
            short4v p = {(short)f2bf(y0), (short)f2bf(y1),
                         (short)f2bf(y2), (short)f2bf(y3)};
            *reinterpret_cast<short4v*>(
                &xbt[n * 128 + (((f0 >> 3) ^ (n & 7)) << 3) + (f0 & 7)]) = p;
          } else {
            xbt[xts(f0 + 0, n)] = f2bf(y0);
            xbt[xts(f0 + 1, n)] = f2bf(y1);
            xbt[xts(f0 + 2, n)] = f2bf(y2);
            xbt[xts(f0 + 3, n)] = f2bf(y3);
          }
        }
      }
    }
  }
  __syncthreads();
}

// ---------------- MEGA: 1 block = 1 molecule; 3 NGF layers + Conv1D + BN + ReLU ----------------
__global__ __launch_bounds__(256, 4) void mega(
    const float* __restrict__ atoms, const int* __restrict__ edges_g,
    const u16* __restrict__ bsum, const u16* __restrict__ wt1,
    const u16* __restrict__ wt2, const u16* __restrict__ wt3,
    const u16* __restrict__ wcf, const float* __restrict__ scale,
    const float* __restrict__ shift, const float* __restrict__ shift2,
    float* __restrict__ out) {
  __shared__ __align__(16) char smem[39808];
  u16* feats = (u16*)smem;                       // [60][160] (reads to row 63 spill into xbt: finite, discarded)
  u16* xbt = (u16*)(smem + 19200);               // [128][64] transposed x; later conv layout [60][128]
  u8* S8 = (u8*)(smem + 35584);                  // [60][64] (reads to row 63 spill into eds: finite)
  signed char* eds = (signed char*)(smem + 39424);
  u8* degs8 = (u8*)(smem + 39728);
  int* presentS = (int*)(smem + 39792);

  const int b = blockIdx.x, tid = threadIdx.x;
  const int lane = tid & 63;
  const int wid = __builtin_amdgcn_readfirstlane(tid >> 6);

  // ---- phase 0: zero feats+S, load edges, load atoms (covers all of xbt) ----
  if (tid == 0) *presentS = 0;
  for (int i = tid; i < 1200; i += 256) ((int4*)feats)[i] = (int4){0, 0, 0, 0};
  for (int i = tid; i < 240; i += 256) ((int4*)S8)[i] = (int4){0, 0, 0, 0};
  for (int i = tid; i < 300; i += 256) eds[i] = (signed char)edges_g[b * 300 + i];
  for (int i = tid; i < 8192; i += 256) {
    int n = i >> 7, c = i & 127;
    float x = (c < 62 && n < 60) ? atoms[(size_t)b * 3720 + n * 62 + c] : 0.f;
    xbt[xts(c, n)] = f2bf(x);
  }
  __syncthreads();

  // ---- phase 1: degrees, presence, S build (single wave; rows owned per-thread) ----
  if (tid < 64) {
    int dgv = 7;
    if (tid < 60) {
      dgv = 0;
      #pragma unroll
      for (int d = 0; d < 5; ++d) dgv += (eds[tid * 5 + d] >= 0);
      atomicOr(presentS, 1 << dgv);
      S8[tid * 64 + tid] = (u8)(S8[tid * 64 + tid] + 1);
      #pragma unroll
      for (int d = 0; d < 5; ++d) {
        int e = eds[tid * 5 + d];
        if (e >= 0) S8[tid * 64 + e] = (u8)(S8[tid * 64 + e] + 1);
      }
    }
    degs8[tid] = (u8)dgv;
  }
  __syncthreads();

  const u16* bsum_b = bsum + (size_t)b * 360;
  layer<1, 64, 3, false>(feats, xbt, S8, degs8, presentS, bsum_b, wt1,
                         scale + 0, shift2 + 0, tid, lane, wid);
  layer<2, 128, 5, false>(feats, xbt, S8, degs8, presentS, bsum_b, wt2,
                          scale + 128, shift2 + 768, tid, lane, wid);
  layer<2, 128, 5, true>(feats, xbt, S8, degs8, presentS, bsum_b, wt3,
                         scale + 256, shift2 + 1536, tid, lane, wid);

  // ---- conv: implicit GEMM over x3 (conv layout in xbt region) ----
  {
    const int fr = lane & 15, rg = lane >> 4;
    const u16* xconv = xbt;
    f32x4 cacc[3][2];
    #pragma unroll
    for (int rt = 0; rt < 3; ++rt)
      #pragma unroll
      for (int ct = 0; ct < 2; ++ct) cacc[rt][ct] = (f32x4){0.f, 0.f, 0.f, 0.f};

    bf16x8 br[2][2], ar[2][3];
    auto loadB = [&](int ks, int slot) {
      #pragma unroll
      for (int nt = 0; nt < 2; ++nt)
        br[slot][nt] = *reinterpret_cast<const bf16x8*>(
            &wcf[(((size_t)ks * 8 + wid * 2 + nt) * 64 + lane) * 8]);
    };
    auto loadA = [&](int ks, int slot) {
      int rowadd = ks >> 2;
      int unit = ((ks & 3) << 2) + rg;
      #pragma unroll
      for (int rt = 0; rt < 3; ++rt) {
        int arow = rt * 16 + fr + rowadd;   // <= 62; rows>=60 garbage, rows t>=45 discarded
        int uo = unit ^ (arow & 7);
        ar[slot][rt] = *reinterpret_cast<const bf16x8*>(&xconv[arow * 128 + uo * 8]);
      }
    };
    loadB(0, 0); loadB(1, 1); loadA(0, 0);
    #pragma unroll 2
    for (int ks = 0; ks < 64; ++ks) {
      if (ks < 63) loadA(ks + 1, (ks + 1) & 1);
      #pragma unroll
      for (int rt = 0; rt < 3; ++rt)
        #pragma unroll
        for (int ct = 0; ct < 2; ++ct)
          cacc[rt][ct] = __builtin_amdgcn_mfma_f32_16x16x32_bf16(
              ar[ks & 1][rt], br[ks & 1][ct], cacc[rt][ct], 0, 0, 0);
      if (ks < 62) loadB(ks + 2, ks & 1);
    }

    #pragma unroll
    for (int ct = 0; ct < 2; ++ct) {
      int f = wid * 32 + ct * 16 + fr;
      float sc = scale[384 + f], sh = shift[384 + f];
      #pragma unroll
      for (int rt = 0; rt < 3; ++rt) {
        #pragma unroll
        for (int j = 0; j < 4; ++j) {
          int t = rt * 16 + rg * 4 + j;
          if (t < 45) {
            float y = fmaxf(cacc[rt][ct][j] * sc + sh, 0.f);
            out[((size_t)b * 45 + t) * 128 + f] = y;
          }
        }
      }
    }
  }
}

extern "C" void kernel_launch(void* const* d_in, const int* in_sizes, int n_in,
                              void* d_out, int out_size, void* d_ws, size_t ws_size,
                              hipStream_t stream) {
  const float* atoms = (const float*)d_in[0];
  const float* bonds = (const float*)d_in[1];
  const int*   edges = (const int*)d_in[2];
  const float* W1 = (const float*)d_in[3]; const float* b1 = (const float*)d_in[4];
  const float* W2 = (const float*)d_in[5]; const float* b2 = (const float*)d_in[6];
  const float* W3 = (const float*)d_in[7]; const float* b3 = (const float*)d_in[8];
  const float* Wc = (const float*)d_in[9];

  char* ws = (char*)d_ws;
  float* scale  = (float*)(ws + OFF_BN);
  float* shift  = scale + 512;
  float* shift2 = (float*)(ws + OFF_SH2);
  u16*   bsum   = (u16*)(ws + OFF_BSUM);
  u16*   wt1    = (u16*)(ws + OFF_WT1);
  u16*   wt2    = (u16*)(ws + OFF_WT2);
  u16*   wt3    = (u16*)(ws + OFF_WT3);
  u16*   wcf    = (u16*)(ws + OFF_WCF);

  prep<<<775, 256, 0, stream>>>(
      bonds, Wc, W1, W2, W3,
      (const float*)d_in[10], (const float*)d_in[11], (const float*)d_in[12], (const float*)d_in[13],
      (const float*)d_in[14], (const float*)d_in[15], (const float*)d_in[16], (const float*)d_in[17],
      (const float*)d_in[18], (const float*)d_in[19], (const float*)d_in[20], (const float*)d_in[21],
      (const float*)d_in[22], (const float*)d_in[23], (const float*)d_in[24], (const float*)d_in[25],
      b1, b2, b3, scale, shift, shift2, bsum, wt1, wt2, wt3, wcf);

  mega<<<1024, 256, 0, stream>>>(atoms, edges, bsum, wt1, wt2, wt3, wcf,
                                 scale, shift, shift2, (float*)d_out);
}

// Round 6
// 202.924 us; speedup vs baseline: 2.3791x; 1.0638x over previous
//
#include <hip/hip_runtime.h>
#include <hip/hip_bf16.h>

typedef __attribute__((ext_vector_type(8))) short bf16x8;
typedef __attribute__((ext_vector_type(4))) short short4v;
typedef __attribute__((ext_vector_type(4))) float f32x4;
typedef unsigned short u16;
typedef unsigned char u8;

// dims: B=1024 N=60 D=5 Fa=62 Fb=6 width=128; conv KSZ=16 FILT=128 Tout=45
static constexpr size_t OFF_BN   = 0;        // scale[4][128]+shift[4][128] = 4096
static constexpr size_t OFF_SH2  = 4096;     // shift2[3][6][128] f32 = 9216
static constexpr size_t OFF_BSUM = 13312;    // 61440*6*2 = 737280
static constexpr size_t OFF_WT1  = 750592;   // 6*3*8*64*8*2 = 147456
static constexpr size_t OFF_WT2  = 898048;   // 6*5*8*64*8*2 = 245760
static constexpr size_t OFF_WT3  = 1143808;  // 245760
static constexpr size_t OFF_WCF  = 1389568;  // 64*8*64*8*2 = 524288 -> ends 1913856

__device__ __forceinline__ float bf2f(u16 r) {
  union { unsigned u; float f; } cv; cv.u = ((unsigned)r) << 16; return cv.f;
}
__device__ __forceinline__ u16 f2bf(float x) {
  __hip_bfloat16 h = __float2bfloat16(x); return *(u16*)&h;
}
// feats layout: [n][160] u16, unit swizzle u' = (u<16) ? u^(n&7) : u
__device__ __forceinline__ int fidx(int n, int c) {
  int u = c >> 3;
  int uu = (u < 16) ? (u ^ (n & 7)) : u;
  return n * 160 + (uu << 3) + (c & 7);
}

// ---------------- merged prep kernel (unchanged from R5) ----------------
__device__ __forceinline__ void emit_wt(u16* dst, const float* W, int FIN, int FIN_A,
                                        int CB, int KSTEPS, int v) {
  int lane = v & 63;
  int ftile = (v >> 6) & 7;
  int ks = (v >> 9) % KSTEPS;
  int d = (v >> 9) / KSTEPS;
  int f = ftile * 16 + (lane & 15);
  int k0 = ks * 32 + (lane >> 4) * 8;
  bf16x8 o;
  #pragma unroll
  for (int i = 0; i < 8; ++i) {
    int k = k0 + i;
    int src = (k < FIN_A) ? k : (k >= CB && k < CB + 6) ? (FIN_A + k - CB) : -1;
    float x = (src >= 0) ? W[((size_t)d * FIN + src) * 128 + f] : 0.f;
    o[i] = (short)f2bf(x);
  }
  *reinterpret_cast<bf16x8*>(&dst[(size_t)v * 8]) = o;
}

__global__ __launch_bounds__(256) void prep(
    const float* __restrict__ bonds, const float* __restrict__ Wc,
    const float* __restrict__ W1, const float* __restrict__ W2, const float* __restrict__ W3,
    const float* g1, const float* be1, const float* m1, const float* v1,
    const float* g2, const float* be2, const float* m2, const float* v2,
    const float* g3, const float* be3, const float* m3, const float* v3,
    const float* g4, const float* be4, const float* m4, const float* v4,
    const float* bb1, const float* bb2, const float* bb3,
    float* __restrict__ scale, float* __restrict__ shift, float* __restrict__ shift2,
    u16* __restrict__ bsum, u16* __restrict__ wt1, u16* __restrict__ wt2,
    u16* __restrict__ wt3, u16* __restrict__ wcf) {
  __shared__ float sb[3840];
  const int b = blockIdx.x, tid = threadIdx.x;
  if (b < 480) {                       // bond sums, 128 atoms/block
    const int base = b * 128;
    const float4* src = (const float4*)(bonds + (size_t)base * 30);
    for (int i = tid; i < 960; i += 256) ((float4*)sb)[i] = src[i];
    __syncthreads();
    if (tid < 128) {
      float s[6] = {0.f, 0.f, 0.f, 0.f, 0.f, 0.f};
      #pragma unroll
      for (int d = 0; d < 5; ++d)
        #pragma unroll
        for (int j = 0; j < 6; ++j) s[j] += sb[tid * 30 + d * 6 + j];
      #pragma unroll
      for (int j = 0; j < 6; ++j) bsum[(size_t)(base + tid) * 6 + j] = f2bf(s[j]);
    }
  } else if (b < 608) {                // wcf: Wc [16][128][128] -> fragment-major
    int v = (b - 480) * 256 + tid;
    int lane = v & 63, ftile = (v >> 6) & 7, ks = v >> 9;
    int f = ftile * 16 + (lane & 15);
    int k0 = ks * 32 + (lane >> 4) * 8;
    int tap = k0 >> 7, ch0 = k0 & 127;
    bf16x8 o;
    #pragma unroll
    for (int i = 0; i < 8; ++i)
      o[i] = (short)f2bf(Wc[((size_t)tap * 128 + ch0 + i) * 128 + f]);
    *reinterpret_cast<bf16x8*>(&wcf[(size_t)v * 8]) = o;
  } else if (b < 644) {
    emit_wt(wt1, W1, 68, 62, 64, 3, (b - 608) * 256 + tid);
  } else if (b < 704) {
    emit_wt(wt2, W2, 134, 128, 128, 5, (b - 644) * 256 + tid);
  } else if (b < 764) {
    emit_wt(wt3, W3, 134, 128, 128, 5, (b - 704) * 256 + tid);
  } else if (b < 766) {                // BN scale/shift
    int idx = (b - 764) * 256 + tid;
    const float* gs[4] = {g1, g2, g3, g4};
    const float* bs[4] = {be1, be2, be3, be4};
    const float* ms[4] = {m1, m2, m3, m4};
    const float* vs[4] = {v1, v2, v3, v4};
    int l = idx >> 7, ch = idx & 127;
    float sc = gs[l][ch] / sqrtf(vs[l][ch] + 1e-3f);   // keras BN epsilon
    scale[idx] = sc;
    shift[idx] = bs[l][ch] - ms[l][ch] * sc;
  } else {                             // shift2 = folded per-degree bias
    int i = (b - 766) * 256 + tid;
    if (i < 2304) {
      const float* G[3] = {g1, g2, g3};
      const float* Be[3] = {be1, be2, be3};
      const float* M[3] = {m1, m2, m3};
      const float* V[3] = {v1, v2, v3};
      const float* Bl[3] = {bb1, bb2, bb3};
      int ll = i / 768, r = i % 768, f = r & 127;
      float sc = G[ll][f] / sqrtf(V[ll][f] + 1e-3f);
      float sh = Be[ll][f] - M[ll][f] * sc;
      shift2[i] = Bl[ll][r] * sc + sh;
    }
  }
}

// ---------------- per-layer body ----------------
// Layers 1-2 (!TOCONV): OUT[n][f] = mfma(feats_frag, wtf_frag) -> b64 epilogue writes
// Layer 3 (TOCONV): OUT^T[f][n] = mfma(wtf_frag, feats_frag) -> short4v conv-layout writes
// Per-degree results selected into racc registers; ONE write pass at the end.
template <int MPW, int CB, int KSTEPS, bool TOCONV>
__device__ __forceinline__ void layer(
    u16* __restrict__ feats, u16* __restrict__ xbt,
    const u8* __restrict__ S8, const u8* __restrict__ degs8,
    const int* __restrict__ presentS, const u16* __restrict__ bsum_b,
    const u16* __restrict__ wtf, const float* __restrict__ sc_l,
    const float* __restrict__ sh2_l, int tid, int lane, int wid) {
  const int fr = lane & 15, rg = lane >> 4;

  // ---- S fragments: u8 -> bf16 ----
  bf16x8 sf[4][2];
  #pragma unroll
  for (int nt = 0; nt < 4; ++nt) {
    #pragma unroll
    for (int ks = 0; ks < 2; ++ks) {
      int n = nt * 16 + fr, m0 = ks * 32 + rg * 8;
      const unsigned* wp = (const unsigned*)(S8 + n * 64 + m0);
      unsigned lo = wp[0], hi = wp[1];
      bf16x8 v;
      #pragma unroll
      for (int i = 0; i < 4; ++i) v[i] = (short)f2bf((float)((lo >> (i * 8)) & 255u));
      #pragma unroll
      for (int i = 0; i < 4; ++i) v[4 + i] = (short)f2bf((float)((hi >> (i * 8)) & 255u));
      sf[nt][ks] = v;
    }
  }

  // ---- gather GEMM: D^T[c][n] = (x^T)(S^T); A = xbt rows, B = S frags ----
  f32x4 gacc[MPW][4];
  #pragma unroll
  for (int mt = 0; mt < MPW; ++mt)
    #pragma unroll
    for (int nt = 0; nt < 4; ++nt) gacc[mt][nt] = (f32x4){0.f, 0.f, 0.f, 0.f};
  #pragma unroll
  for (int mt = 0; mt < MPW; ++mt) {
    const int c = (wid * MPW + mt) * 16 + fr;
    #pragma unroll
    for (int ks = 0; ks < 2; ++ks) {
      const int m0 = ks * 32 + rg * 8;
      bf16x8 a = *reinterpret_cast<const bf16x8*>(
          &xbt[c * 64 + (((m0 >> 3) ^ (c & 7)) << 3)]);
      #pragma unroll
      for (int nt = 0; nt < 4; ++nt)
        gacc[mt][nt] = __builtin_amdgcn_mfma_f32_16x16x32_bf16(a, sf[nt][ks],
                                                               gacc[mt][nt], 0, 0, 0);
    }
  }
  // write feats (short4v along c, swizzled)
  #pragma unroll
  for (int mt = 0; mt < MPW; ++mt) {
    const int c0 = (wid * MPW + mt) * 16 + rg * 4;
    const int uu = c0 >> 3;                          // < 16
    #pragma unroll
    for (int nt = 0; nt < 4; ++nt) {
      const int n = nt * 16 + fr;
      if (n < 60) {
        short4v p;
        #pragma unroll
        for (int j = 0; j < 4; ++j) p[j] = (short)f2bf(gacc[mt][nt][j]);
        *reinterpret_cast<short4v*>(
            &feats[n * 160 + ((uu ^ (n & 7)) << 3) + (c0 & 7)]) = p;
      }
    }
  }
  // bond-sum cols
  for (int i = tid; i < 360; i += 256) {
    int n = i / 6, c = CB + (i % 6);
    feats[fidx(n, c)] = bsum_b[i];
  }
  __syncthreads();

  const int pres = *presentS;

  if constexpr (!TOCONV) {
    const int f0w = wid * 32;
    unsigned dgw[4];
    #pragma unroll
    for (int m = 0; m < 4; ++m)
      dgw[m] = *(const unsigned*)(degs8 + m * 16 + rg * 4);
    float scf[2] = {sc_l[f0w + fr], sc_l[f0w + 16 + fr]};
    f32x4 racc[4][2];
    #pragma unroll
    for (int m = 0; m < 4; ++m)
      #pragma unroll
      for (int nf = 0; nf < 2; ++nf) racc[m][nf] = (f32x4){0.f, 0.f, 0.f, 0.f};

    for (int d = 0; d < 6; ++d) {
      if (!(pres & (1 << d))) continue;
      const u16* __restrict__ wd = wtf + (size_t)d * (KSTEPS * 4096);
      f32x4 acc[4][2];
      #pragma unroll
      for (int m = 0; m < 4; ++m)
        #pragma unroll
        for (int nf = 0; nf < 2; ++nf) acc[m][nf] = (f32x4){0.f, 0.f, 0.f, 0.f};
      bf16x8 wring[2][2];
      #pragma unroll
      for (int nf = 0; nf < 2; ++nf)
        wring[0][nf] = *reinterpret_cast<const bf16x8*>(
            &wd[((0 * 8 + wid * 2 + nf) * 64 + lane) * 8]);
      #pragma unroll
      for (int nf = 0; nf < 2; ++nf)
        wring[1][nf] = *reinterpret_cast<const bf16x8*>(
            &wd[((1 * 8 + wid * 2 + nf) * 64 + lane) * 8]);
      #pragma unroll
      for (int ks = 0; ks < KSTEPS; ++ks) {
        bf16x8 afr[4];
        const int u = ks * 4 + rg;
        #pragma unroll
        for (int m = 0; m < 4; ++m) {
          const int n = m * 16 + fr;
          const int uu = (u < 16) ? (u ^ (n & 7)) : u;
          afr[m] = *reinterpret_cast<const bf16x8*>(&feats[n * 160 + (uu << 3)]);
        }
        #pragma unroll
        for (int m = 0; m < 4; ++m)
          #pragma unroll
          for (int nf = 0; nf < 2; ++nf)
            acc[m][nf] = __builtin_amdgcn_mfma_f32_16x16x32_bf16(
                afr[m], wring[ks & 1][nf], acc[m][nf], 0, 0, 0);
        if (ks + 2 < KSTEPS) {
          #pragma unroll
          for (int nf = 0; nf < 2; ++nf)
            wring[ks & 1][nf] = *reinterpret_cast<const bf16x8*>(
                &wd[(((ks + 2) * 8 + wid * 2 + nf) * 64 + lane) * 8]);
        }
      }
      // select into racc
      #pragma unroll
      for (int nf = 0; nf < 2; ++nf) {
        const float sh = sh2_l[d * 128 + f0w + nf * 16 + fr];
        #pragma unroll
        for (int m = 0; m < 4; ++m) {
          #pragma unroll
          for (int j = 0; j < 4; ++j) {
            float y = fmaxf(acc[m][nf][j] * scf[nf] + sh, 0.f);
            bool sel = (((dgw[m] >> (8 * j)) & 255u) == (unsigned)d);
            racc[m][nf][j] = sel ? y : racc[m][nf][j];
          }
        }
      }
    }
    // single b64 write pass (n-quads >= 60 skipped -> xbt pad rows stay zero)
    #pragma unroll
    for (int m = 0; m < 4; ++m) {
      const int n0 = m * 16 + rg * 4;
      if (n0 < 60) {
        #pragma unroll
        for (int nf = 0; nf < 2; ++nf) {
          const int c = f0w + nf * 16 + fr;
          short4v p;
          #pragma unroll
          for (int j = 0; j < 4; ++j) p[j] = (short)f2bf(racc[m][nf][j]);
          *reinterpret_cast<short4v*>(
              &xbt[c * 64 + (((n0 >> 3) ^ (c & 7)) << 3) + (n0 & 7)]) = p;
        }
      }
    }
  } else {
    int dgn[4];
    #pragma unroll
    for (int nt = 0; nt < 4; ++nt) dgn[nt] = degs8[nt * 16 + fr];
    f32x4 scv[2];
    #pragma unroll
    for (int mt = 0; mt < 2; ++mt)
      scv[mt] = *reinterpret_cast<const f32x4*>(&sc_l[(wid * 2 + mt) * 16 + rg * 4]);
    f32x4 racc[2][4];
    #pragma unroll
    for (int mt = 0; mt < 2; ++mt)
      #pragma unroll
      for (int nt = 0; nt < 4; ++nt) racc[mt][nt] = (f32x4){0.f, 0.f, 0.f, 0.f};

    for (int d = 0; d < 6; ++d) {
      if (!(pres & (1 << d))) continue;
      const u16* __restrict__ wd = wtf + (size_t)d * (KSTEPS * 4096);
      f32x4 acc[2][4];
      #pragma unroll
      for (int mt = 0; mt < 2; ++mt)
        #pragma unroll
        for (int nt = 0; nt < 4; ++nt) acc[mt][nt] = (f32x4){0.f, 0.f, 0.f, 0.f};
      bf16x8 wring[2][2];
      #pragma unroll
      for (int mt = 0; mt < 2; ++mt)
        wring[0][mt] = *reinterpret_cast<const bf16x8*>(
            &wd[((0 * 8 + wid * 2 + mt) * 64 + lane) * 8]);
      #pragma unroll
      for (int mt = 0; mt < 2; ++mt)
        wring[1][mt] = *reinterpret_cast<const bf16x8*>(
            &wd[((1 * 8 + wid * 2 + mt) * 64 + lane) * 8]);
      #pragma unroll
      for (int ks = 0; ks < KSTEPS; ++ks) {
        bf16x8 bfr[4];
        const int u = ks * 4 + rg;
        #pragma unroll
        for (int nt = 0; nt < 4; ++nt) {
          const int n = nt * 16 + fr;
          const int uu = (u < 16) ? (u ^ (n & 7)) : u;
          bfr[nt] = *reinterpret_cast<const bf16x8*>(&feats[n * 160 + (uu << 3)]);
        }
        #pragma unroll
        for (int mt = 0; mt < 2; ++mt)
          #pragma unroll
          for (int nt = 0; nt < 4; ++nt)
            acc[mt][nt] = __builtin_amdgcn_mfma_f32_16x16x32_bf16(
                wring[ks & 1][mt], bfr[nt], acc[mt][nt], 0, 0, 0);
        if (ks + 2 < KSTEPS) {
          #pragma unroll
          for (int mt = 0; mt < 2; ++mt)
            wring[ks & 1][mt] = *reinterpret_cast<const bf16x8*>(
                &wd[(((ks + 2) * 8 + wid * 2 + mt) * 64 + lane) * 8]);
        }
      }
      #pragma unroll
      for (int mt = 0; mt < 2; ++mt) {
        f32x4 shv = *reinterpret_cast<const f32x4*>(
            &sh2_l[d * 128 + (wid * 2 + mt) * 16 + rg * 4]);
        #pragma unroll
        for (int nt = 0; nt < 4; ++nt) {
          bool sel = (dgn[nt] == d);
          #pragma unroll
          for (int j = 0; j < 4; ++j) {
            float y = fmaxf(acc[mt][nt][j] * scv[mt][j] + shv[j], 0.f);
            racc[mt][nt][j] = sel ? y : racc[mt][nt][j];
          }
        }
      }
    }
    // conv-layout write [n][128]
    #pragma unroll
    for (int nt = 0; nt < 4; ++nt) {
      const int n = nt * 16 + fr;
      if (n < 60) {
        #pragma unroll
        for (int mt = 0; mt < 2; ++mt) {
          const int f0 = (wid * 2 + mt) * 16 + rg * 4;
          short4v p;
          #pragma unroll
          for (int j = 0; j < 4; ++j) p[j] = (short)f2bf(racc[mt][nt][j]);
          *reinterpret_cast<short4v*>(
              &xbt[n * 128 + (((f0 >> 3) ^ (n & 7)) << 3) + (f0 & 7)]) = p;
        }
      }
    }
  }
  __syncthreads();
}

// ---------------- MEGA: 1 block = 1 molecule ----------------
__global__ __launch_bounds__(256, 4) void mega(
    const float* __restrict__ atoms, const int* __restrict__ edges_g,
    const u16* __restrict__ bsum, const u16* __restrict__ wt1,
    const u16* __restrict__ wt2, const u16* __restrict__ wt3,
    const u16* __restrict__ wcf, const float* __restrict__ scale,
    const float* __restrict__ shift, const float* __restrict__ shift2,
    float* __restrict__ out) {
  __shared__ __align__(16) char smem[39936];
  u16* feats = (u16*)smem;                 // [60][160]; also f32 atom scratch in phase 0
  u16* xbt = (u16*)(smem + 19200);         // [c<=128][64] transposed x; later conv [60][128]
  u8* S8 = (u8*)(smem + 35584);            // [60][64]
  signed char* eds = (signed char*)(smem + 39424);
  u8* degs8 = (u8*)(smem + 39728);
  int* presentS = (int*)(smem + 39792);
  float* fscr = (float*)smem;              // [60][62] f32 staging

  const int b = blockIdx.x, tid = threadIdx.x;
  const int lane = tid & 63;
  const int wid = __builtin_amdgcn_readfirstlane(tid >> 6);

  // ---- phase 0: edges, coalesced atom stage, zero xbt hi-rows + S8 ----
  if (tid == 0) *presentS = 0;
  for (int i = tid; i < 300; i += 256) eds[i] = (signed char)edges_g[b * 300 + i];
  {
    const float4* ag4 = (const float4*)(atoms + (size_t)b * 3720);
    float4* fs4 = (float4*)fscr;
    for (int i = tid; i < 930; i += 256) fs4[i] = ag4[i];   // 60*62 f32
    int4 z4 = {0, 0, 0, 0};
    int4* xz = (int4*)(xbt + 64 * 64);
    for (int i = tid; i < 512; i += 256) xz[i] = z4;        // xbt rows c=64..127
    int4* sz = (int4*)S8;
    for (int i = tid; i < 240; i += 256) sz[i] = z4;
  }
  __syncthreads();

  // ---- phase 1: S build + degrees (wave 0); b128 transpose write c=0..63 ----
  if (tid < 64) {
    int dgv = 7;
    if (tid < 60) {
      dgv = 0;
      #pragma unroll
      for (int d = 0; d < 5; ++d) dgv += (eds[tid * 5 + d] >= 0);
      atomicOr(presentS, 1 << dgv);
      S8[tid * 64 + tid] = (u8)(S8[tid * 64 + tid] + 1);
      #pragma unroll
      for (int d = 0; d < 5; ++d) {
        int e = eds[tid * 5 + d];
        if (e >= 0) S8[tid * 64 + e] = (u8)(S8[tid * 64 + e] + 1);
      }
    }
    degs8[tid] = (u8)dgv;
  }
  for (int id = tid; id < 512; id += 256) {
    int oct = id & 7, c = id >> 3;     // c 0..63, oct = n-octet
    bf16x8 v;
    #pragma unroll
    for (int k = 0; k < 8; ++k) {
      int n = oct * 8 + k;
      float x = (c < 62 && n < 60) ? fscr[n * 62 + c] : 0.f;
      v[k] = (short)f2bf(x);
    }
    *reinterpret_cast<bf16x8*>(&xbt[c * 64 + ((oct ^ (c & 7)) << 3)]) = v;
  }
  __syncthreads();

  // zero perpetual feats pad cols [70,96) & [134,160), rows 0..59
  // (disjoint from gather/bond writes; layer's internal barrier orders the reads)
  for (int i = tid; i < 60 * 52; i += 256) {
    int n = i / 52, q = i % 52;
    int c = (q < 26) ? (70 + q) : (108 + q);
    feats[fidx(n, c)] = 0;
  }

  const u16* bsum_b = bsum + (size_t)b * 360;
  layer<1, 64, 3, false>(feats, xbt, S8, degs8, presentS, bsum_b, wt1,
                         scale + 0, shift2 + 0, tid, lane, wid);
  layer<2, 128, 5, false>(feats, xbt, S8, degs8, presentS, bsum_b, wt2,
                          scale + 128, shift2 + 768, tid, lane, wid);
  layer<2, 128, 5, true>(feats, xbt, S8, degs8, presentS, bsum_b, wt3,
                         scale + 256, shift2 + 1536, tid, lane, wid);

  // ---- conv: implicit GEMM over x3 (conv layout in xbt), 4-deep B ring ----
  {
    const int fr = lane & 15, rg = lane >> 4;
    const u16* xconv = xbt;
    f32x4 cacc[3][2];
    #pragma unroll
    for (int rt = 0; rt < 3; ++rt)
      #pragma unroll
      for (int ct = 0; ct < 2; ++ct) cacc[rt][ct] = (f32x4){0.f, 0.f, 0.f, 0.f};

    bf16x8 br[4][2], ar[2][3];
    auto loadB = [&](int ks, int slot) {
      #pragma unroll
      for (int nt = 0; nt < 2; ++nt)
        br[slot][nt] = *reinterpret_cast<const bf16x8*>(
            &wcf[(((size_t)ks * 8 + wid * 2 + nt) * 64 + lane) * 8]);
    };
    auto loadA = [&](int ks, int slot) {
      int rowadd = ks >> 2;
      int unit = ((ks & 3) << 2) + rg;
      #pragma unroll
      for (int rt = 0; rt < 3; ++rt) {
        int arow = rt * 16 + fr + rowadd;   // <= 62; rows>=60 finite garbage, discarded
        int uo = unit ^ (arow & 7);
        ar[slot][rt] = *reinterpret_cast<const bf16x8*>(&xconv[arow * 128 + uo * 8]);
      }
    };
    loadB(0, 0); loadB(1, 1); loadB(2, 2); loadA(0, 0);
    #pragma unroll 4
    for (int ks = 0; ks < 64; ++ks) {
      if (ks < 63) loadA(ks + 1, (ks + 1) & 1);
      #pragma unroll
      for (int rt = 0; rt < 3; ++rt)
        #pragma unroll
        for (int ct = 0; ct < 2; ++ct)
          cacc[rt][ct] = __builtin_amdgcn_mfma_f32_16x16x32_bf16(
              ar[ks & 1][rt], br[ks & 3][ct], cacc[rt][ct], 0, 0, 0);
      if (ks < 61) loadB(ks + 3, (ks + 3) & 3);
    }

    #pragma unroll
    for (int ct = 0; ct < 2; ++ct) {
      int f = wid * 32 + ct * 16 + fr;
      float sc = scale[384 + f], sh = shift[384 + f];
      #pragma unroll
      for (int rt = 0; rt < 3; ++rt) {
        #pragma unroll
        for (int j = 0; j < 4; ++j) {
          int t = rt * 16 + rg * 4 + j;
          if (t < 45) {
            float y = fmaxf(cacc[rt][ct][j] * sc + sh, 0.f);
            out[((size_t)b * 45 + t) * 128 + f] = y;
          }
        }
      }
    }
  }
}

extern "C" void kernel_launch(void* const* d_in, const int* in_sizes, int n_in,
                              void* d_out, int out_size, void* d_ws, size_t ws_size,
                              hipStream_t stream) {
  const float* atoms = (const float*)d_in[0];
  const float* bonds = (const float*)d_in[1];
  const int*   edges = (const int*)d_in[2];
  const float* W1 = (const float*)d_in[3]; const float* b1 = (const float*)d_in[4];
  const float* W2 = (const float*)d_in[5]; const float* b2 = (const float*)d_in[6];
  const float* W3 = (const float*)d_in[7]; const float* b3 = (const float*)d_in[8];
  const float* Wc = (const float*)d_in[9];

  char* ws = (char*)d_ws;
  float* scale  = (float*)(ws + OFF_BN);
  float* shift  = scale + 512;
  float* shift2 = (float*)(ws + OFF_SH2);
  u16*   bsum   = (u16*)(ws + OFF_BSUM);
  u16*   wt1    = (u16*)(ws + OFF_WT1);
  u16*   wt2    = (u16*)(ws + OFF_WT2);
  u16*   wt3    = (u16*)(ws + OFF_WT3);
  u16*   wcf    = (u16*)(ws + OFF_WCF);

  prep<<<775, 256, 0, stream>>>(
      bonds, Wc, W1, W2, W3,
      (const float*)d_in[10], (const float*)d_in[11], (const float*)d_in[12], (const float*)d_in[13],
      (const float*)d_in[14], (const float*)d_in[15], (const float*)d_in[16], (const float*)d_in[17],
      (const float*)d_in[18], (const float*)d_in[19], (const float*)d_in[20], (const float*)d_in[21],
      (const float*)d_in[22], (const float*)d_in[23], (const float*)d_in[24], (const float*)d_in[25],
      b1, b2, b3, scale, shift, shift2, bsum, wt1, wt2, wt3, wcf);

  mega<<<1024, 256, 0, stream>>>(atoms, edges, bsum, wt1, wt2, wt3, wcf,
                                 scale, shift, shift2, (float*)d_out);
}

// Round 7
// 200.839 us; speedup vs baseline: 2.4038x; 1.0104x over previous
//
#include <hip/hip_runtime.h>
#include <hip/hip_bf16.h>

typedef __attribute__((ext_vector_type(8))) short bf16x8;
typedef __attribute__((ext_vector_type(4))) short short4v;
typedef __attribute__((ext_vector_type(4))) float f32x4;
typedef unsigned short u16;
typedef unsigned char u8;

// dims: B=1024 N=60 D=5 Fa=62 Fb=6 width=128; conv KSZ=16 FILT=128 Tout=45
static constexpr size_t OFF_BN   = 0;        // scale[4][128]+shift[4][128] = 4096
static constexpr size_t OFF_SH2  = 4096;     // shift2[3][6][128] f32 = 9216
static constexpr size_t OFF_BSUM = 13312;    // 61440*6*2 = 737280
static constexpr size_t OFF_WT1  = 750592;   // 6*3*8*64*8*2 = 147456
static constexpr size_t OFF_WT2  = 898048;   // 6*5*8*64*8*2 = 245760
static constexpr size_t OFF_WT3  = 1143808;  // 245760
static constexpr size_t OFF_WCF  = 1389568;  // 64*8*64*8*2 = 524288 -> ends 1913856

__device__ __forceinline__ float bf2f(u16 r) {
  union { unsigned u; float f; } cv; cv.u = ((unsigned)r) << 16; return cv.f;
}
__device__ __forceinline__ u16 f2bf(float x) {
  __hip_bfloat16 h = __float2bfloat16(x); return *(u16*)&h;
}
// feats layout: [n][160] u16, unit swizzle u' = (u<16) ? u^(n&7) : u
__device__ __forceinline__ int fidx(int n, int c) {
  int u = c >> 3;
  int uu = (u < 16) ? (u ^ (n & 7)) : u;
  return n * 160 + (uu << 3) + (c & 7);
}

// ---------------- merged prep kernel (unchanged, proven R5/R6) ----------------
__device__ __forceinline__ void emit_wt(u16* dst, const float* W, int FIN, int FIN_A,
                                        int CB, int KSTEPS, int v) {
  int lane = v & 63;
  int ftile = (v >> 6) & 7;
  int ks = (v >> 9) % KSTEPS;
  int d = (v >> 9) / KSTEPS;
  int f = ftile * 16 + (lane & 15);
  int k0 = ks * 32 + (lane >> 4) * 8;
  bf16x8 o;
  #pragma unroll
  for (int i = 0; i < 8; ++i) {
    int k = k0 + i;
    int src = (k < FIN_A) ? k : (k >= CB && k < CB + 6) ? (FIN_A + k - CB) : -1;
    float x = (src >= 0) ? W[((size_t)d * FIN + src) * 128 + f] : 0.f;
    o[i] = (short)f2bf(x);
  }
  *reinterpret_cast<bf16x8*>(&dst[(size_t)v * 8]) = o;
}

__global__ __launch_bounds__(256) void prep(
    const float* __restrict__ bonds, const float* __restrict__ Wc,
    const float* __restrict__ W1, const float* __restrict__ W2, const float* __restrict__ W3,
    const float* g1, const float* be1, const float* m1, const float* v1,
    const float* g2, const float* be2, const float* m2, const float* v2,
    const float* g3, const float* be3, const float* m3, const float* v3,
    const float* g4, const float* be4, const float* m4, const float* v4,
    const float* bb1, const float* bb2, const float* bb3,
    float* __restrict__ scale, float* __restrict__ shift, float* __restrict__ shift2,
    u16* __restrict__ bsum, u16* __restrict__ wt1, u16* __restrict__ wt2,
    u16* __restrict__ wt3, u16* __restrict__ wcf) {
  __shared__ float sb[3840];
  const int b = blockIdx.x, tid = threadIdx.x;
  if (b < 480) {                       // bond sums, 128 atoms/block
    const int base = b * 128;
    const float4* src = (const float4*)(bonds + (size_t)base * 30);
    for (int i = tid; i < 960; i += 256) ((float4*)sb)[i] = src[i];
    __syncthreads();
    if (tid < 128) {
      float s[6] = {0.f, 0.f, 0.f, 0.f, 0.f, 0.f};
      #pragma unroll
      for (int d = 0; d < 5; ++d)
        #pragma unroll
        for (int j = 0; j < 6; ++j) s[j] += sb[tid * 30 + d * 6 + j];
      #pragma unroll
      for (int j = 0; j < 6; ++j) bsum[(size_t)(base + tid) * 6 + j] = f2bf(s[j]);
    }
  } else if (b < 608) {                // wcf: Wc [16][128][128] -> fragment-major
    int v = (b - 480) * 256 + tid;
    int lane = v & 63, ftile = (v >> 6) & 7, ks = v >> 9;
    int f = ftile * 16 + (lane & 15);
    int k0 = ks * 32 + (lane >> 4) * 8;
    int tap = k0 >> 7, ch0 = k0 & 127;
    bf16x8 o;
    #pragma unroll
    for (int i = 0; i < 8; ++i)
      o[i] = (short)f2bf(Wc[((size_t)tap * 128 + ch0 + i) * 128 + f]);
    *reinterpret_cast<bf16x8*>(&wcf[(size_t)v * 8]) = o;
  } else if (b < 644) {
    emit_wt(wt1, W1, 68, 62, 64, 3, (b - 608) * 256 + tid);
  } else if (b < 704) {
    emit_wt(wt2, W2, 134, 128, 128, 5, (b - 644) * 256 + tid);
  } else if (b < 764) {
    emit_wt(wt3, W3, 134, 128, 128, 5, (b - 704) * 256 + tid);
  } else if (b < 766) {                // BN scale/shift
    int idx = (b - 764) * 256 + tid;
    const float* gs[4] = {g1, g2, g3, g4};
    const float* bs[4] = {be1, be2, be3, be4};
    const float* ms[4] = {m1, m2, m3, m4};
    const float* vs[4] = {v1, v2, v3, v4};
    int l = idx >> 7, ch = idx & 127;
    float sc = gs[l][ch] / sqrtf(vs[l][ch] + 1e-3f);   // keras BN epsilon
    scale[idx] = sc;
    shift[idx] = bs[l][ch] - ms[l][ch] * sc;
  } else {                             // shift2 = folded per-degree bias
    int i = (b - 766) * 256 + tid;
    if (i < 2304) {
      const float* G[3] = {g1, g2, g3};
      const float* Be[3] = {be1, be2, be3};
      const float* M[3] = {m1, m2, m3};
      const float* V[3] = {v1, v2, v3};
      const float* Bl[3] = {bb1, bb2, bb3};
      int ll = i / 768, r = i % 768, f = r & 127;
      float sc = G[ll][f] / sqrtf(V[ll][f] + 1e-3f);
      float sh = Be[ll][f] - M[ll][f] * sc;
      shift2[i] = Bl[ll][r] * sc + sh;
    }
  }
}

// ---------------- per-layer body (2 molecules, 8 waves, 16-f slices) ----------------
// Gather: wave w -> mol w&1, c-tiles (w>>1)*MPW..; MFMA via S matrix (regs).
// Main GEMM: every wave does BOTH mols' 8 M-tiles with ONE 16-f weight ring
// (halves weight L1 traffic per molecule). Per-(mol,tile,degree) skip masks.
template <int MPW, int CB, int KSTEPS, bool TOCONV>
__device__ __forceinline__ void layer(
    u16* __restrict__ feats, u16* __restrict__ xbt,
    const u8* __restrict__ S8, const u8* __restrict__ degs8,
    const int* __restrict__ presentS, const int* __restrict__ tilemask,
    const u16* __restrict__ bsum2, const u16* __restrict__ wtf,
    const float* __restrict__ sc_l, const float* __restrict__ sh2_l,
    int tid, int lane, int w) {
  const int fr = lane & 15, rg = lane >> 4;
  const int gmol = w & 1;
  const u16* __restrict__ xm = xbt + gmol * 8192;
  u16* __restrict__ fm = feats + gmol * 9600;
  const u8* __restrict__ Sm = S8 + gmol * 4096;

  // ---- S fragments (u8 -> bf16) for this wave's gather molecule ----
  bf16x8 sf[4][2];
  #pragma unroll
  for (int nt = 0; nt < 4; ++nt) {
    #pragma unroll
    for (int ks = 0; ks < 2; ++ks) {
      int n = nt * 16 + fr, m0 = ks * 32 + rg * 8;
      const unsigned* wp = (const unsigned*)(Sm + n * 64 + m0);
      unsigned lo = wp[0], hi = wp[1];
      bf16x8 v;
      #pragma unroll
      for (int i = 0; i < 4; ++i) v[i] = (short)f2bf((float)((lo >> (i * 8)) & 255u));
      #pragma unroll
      for (int i = 0; i < 4; ++i) v[4 + i] = (short)f2bf((float)((hi >> (i * 8)) & 255u));
      sf[nt][ks] = v;
    }
  }

  // ---- gather GEMM: D^T[c][n] = (x^T)(S^T) ----
  f32x4 gacc[MPW][4];
  #pragma unroll
  for (int mt = 0; mt < MPW; ++mt)
    #pragma unroll
    for (int nt = 0; nt < 4; ++nt) gacc[mt][nt] = (f32x4){0.f, 0.f, 0.f, 0.f};
  #pragma unroll
  for (int mt = 0; mt < MPW; ++mt) {
    const int c = ((w >> 1) * MPW + mt) * 16 + fr;
    #pragma unroll
    for (int ks = 0; ks < 2; ++ks) {
      const int m0 = ks * 32 + rg * 8;
      bf16x8 a = *reinterpret_cast<const bf16x8*>(
          &xm[c * 64 + (((m0 >> 3) ^ (c & 7)) << 3)]);
      #pragma unroll
      for (int nt = 0; nt < 4; ++nt)
        gacc[mt][nt] = __builtin_amdgcn_mfma_f32_16x16x32_bf16(a, sf[nt][ks],
                                                               gacc[mt][nt], 0, 0, 0);
    }
  }
  #pragma unroll
  for (int mt = 0; mt < MPW; ++mt) {
    const int c0 = ((w >> 1) * MPW + mt) * 16 + rg * 4;
    const int uu = c0 >> 3;                          // < 16
    #pragma unroll
    for (int nt = 0; nt < 4; ++nt) {
      const int n = nt * 16 + fr;
      if (n < 60) {
        short4v p;
        #pragma unroll
        for (int j = 0; j < 4; ++j) p[j] = (short)f2bf(gacc[mt][nt][j]);
        *reinterpret_cast<short4v*>(
            &fm[n * 160 + ((uu ^ (n & 7)) << 3) + (c0 & 7)]) = p;
      }
    }
  }
  // bond-sum cols (both mols)
  for (int i = tid; i < 720; i += 512) {
    int m2 = (i >= 360) ? 1 : 0;
    int j = i - m2 * 360;
    int n = j / 6, c = CB + (j % 6);
    feats[m2 * 9600 + fidx(n, c)] = bsum2[m2 * 360 + j];
  }
  __syncthreads();

  // ---- main GEMM per present degree: both mols share the weight ring ----
  const int presU = __builtin_amdgcn_readfirstlane(presentS[0] | presentS[1]);
  f32x4 racc[8];
  #pragma unroll
  for (int t = 0; t < 8; ++t) racc[t] = (f32x4){0.f, 0.f, 0.f, 0.f};

  if constexpr (!TOCONV) {
    unsigned dgw[8];
    #pragma unroll
    for (int m2 = 0; m2 < 2; ++m2)
      #pragma unroll
      for (int nt = 0; nt < 4; ++nt)
        dgw[m2 * 4 + nt] = *(const unsigned*)(degs8 + m2 * 64 + nt * 16 + rg * 4);
    const float scf = sc_l[w * 16 + fr];

    for (int d = 0; d < 6; ++d) {
      if (!(presU & (1 << d))) continue;
      const int tm0 = __builtin_amdgcn_readfirstlane(tilemask[d]);
      const int tm1 = __builtin_amdgcn_readfirstlane(tilemask[6 + d]);
      const u16* __restrict__ wd = wtf + (size_t)d * (KSTEPS * 4096);
      f32x4 acc[8];
      #pragma unroll
      for (int t = 0; t < 8; ++t) acc[t] = (f32x4){0.f, 0.f, 0.f, 0.f};
      bf16x8 wring[2];
      wring[0] = *reinterpret_cast<const bf16x8*>(&wd[((0 * 8 + w) * 64 + lane) * 8]);
      wring[1] = *reinterpret_cast<const bf16x8*>(&wd[((1 * 8 + w) * 64 + lane) * 8]);
      #pragma unroll
      for (int ks = 0; ks < KSTEPS; ++ks) {
        const int u = ks * 4 + rg;
        #pragma unroll
        for (int m2 = 0; m2 < 2; ++m2) {
          const int tmv = m2 ? tm1 : tm0;
          #pragma unroll
          for (int nt = 0; nt < 4; ++nt) {
            if (tmv & (1 << nt)) {
              const int n = nt * 16 + fr;
              const int uu = (u < 16) ? (u ^ (n & 7)) : u;
              bf16x8 afr = *reinterpret_cast<const bf16x8*>(
                  &feats[m2 * 9600 + n * 160 + (uu << 3)]);
              acc[m2 * 4 + nt] = __builtin_amdgcn_mfma_f32_16x16x32_bf16(
                  afr, wring[ks & 1], acc[m2 * 4 + nt], 0, 0, 0);
            }
          }
        }
        if (ks + 2 < KSTEPS)
          wring[ks & 1] = *reinterpret_cast<const bf16x8*>(
              &wd[(((ks + 2) * 8 + w) * 64 + lane) * 8]);
      }
      const float sh = sh2_l[d * 128 + w * 16 + fr];
      #pragma unroll
      for (int m2 = 0; m2 < 2; ++m2) {
        const int tmv = m2 ? tm1 : tm0;
        #pragma unroll
        for (int nt = 0; nt < 4; ++nt) {
          if (tmv & (1 << nt)) {
            const int tt = m2 * 4 + nt;
            #pragma unroll
            for (int j = 0; j < 4; ++j) {
              float y = fmaxf(acc[tt][j] * scf + sh, 0.f);
              bool sel = (((dgw[tt] >> (8 * j)) & 255u) == (unsigned)d);
              racc[tt][j] = sel ? y : racc[tt][j];
            }
          }
        }
      }
    }
    // single b64 write pass into transposed xbt
    #pragma unroll
    for (int m2 = 0; m2 < 2; ++m2) {
      #pragma unroll
      for (int nt = 0; nt < 4; ++nt) {
        const int n0 = nt * 16 + rg * 4;
        if (n0 < 60) {
          const int c = w * 16 + fr;
          short4v p;
          #pragma unroll
          for (int j = 0; j < 4; ++j) p[j] = (short)f2bf(racc[m2 * 4 + nt][j]);
          *reinterpret_cast<short4v*>(
              &xbt[m2 * 8192 + c * 64 + (((n0 >> 3) ^ (c & 7)) << 3) + (n0 & 7)]) = p;
        }
      }
    }
  } else {
    int dgn[8];
    #pragma unroll
    for (int m2 = 0; m2 < 2; ++m2)
      #pragma unroll
      for (int nt = 0; nt < 4; ++nt)
        dgn[m2 * 4 + nt] = degs8[m2 * 64 + nt * 16 + fr];
    f32x4 scv = *reinterpret_cast<const f32x4*>(&sc_l[w * 16 + rg * 4]);

    for (int d = 0; d < 6; ++d) {
      if (!(presU & (1 << d))) continue;
      const int tm0 = __builtin_amdgcn_readfirstlane(tilemask[d]);
      const int tm1 = __builtin_amdgcn_readfirstlane(tilemask[6 + d]);
      const u16* __restrict__ wd = wtf + (size_t)d * (KSTEPS * 4096);
      f32x4 acc[8];
      #pragma unroll
      for (int t = 0; t < 8; ++t) acc[t] = (f32x4){0.f, 0.f, 0.f, 0.f};
      bf16x8 wring[2];
      wring[0] = *reinterpret_cast<const bf16x8*>(&wd[((0 * 8 + w) * 64 + lane) * 8]);
      wring[1] = *reinterpret_cast<const bf16x8*>(&wd[((1 * 8 + w) * 64 + lane) * 8]);
      #pragma unroll
      for (int ks = 0; ks < KSTEPS; ++ks) {
        const int u = ks * 4 + rg;
        #pragma unroll
        for (int m2 = 0; m2 < 2; ++m2) {
          const int tmv = m2 ? tm1 : tm0;
          #pragma unroll
          for (int nt = 0; nt < 4; ++nt) {
            if (tmv & (1 << nt)) {
              const int n = nt * 16 + fr;
              const int uu = (u < 16) ? (u ^ (n & 7)) : u;
              bf16x8 bfr = *reinterpret_cast<const bf16x8*>(
                  &feats[m2 * 9600 + n * 160 + (uu << 3)]);
              acc[m2 * 4 + nt] = __builtin_amdgcn_mfma_f32_16x16x32_bf16(
                  wring[ks & 1], bfr, acc[m2 * 4 + nt], 0, 0, 0);
            }
          }
        }
        if (ks + 2 < KSTEPS)
          wring[ks & 1] = *reinterpret_cast<const bf16x8*>(
              &wd[(((ks + 2) * 8 + w) * 64 + lane) * 8]);
      }
      f32x4 shv = *reinterpret_cast<const f32x4*>(&sh2_l[d * 128 + w * 16 + rg * 4]);
      #pragma unroll
      for (int m2 = 0; m2 < 2; ++m2) {
        const int tmv = m2 ? tm1 : tm0;
        #pragma unroll
        for (int nt = 0; nt < 4; ++nt) {
          if (tmv & (1 << nt)) {
            const int tt = m2 * 4 + nt;
            bool sel = (dgn[tt] == d);
            #pragma unroll
            for (int j = 0; j < 4; ++j) {
              float y = fmaxf(acc[tt][j] * scv[j] + shv[j], 0.f);
              racc[tt][j] = sel ? y : racc[tt][j];
            }
          }
        }
      }
    }
    // conv-layout write [n][128] into xbt region
    #pragma unroll
    for (int m2 = 0; m2 < 2; ++m2) {
      #pragma unroll
      for (int nt = 0; nt < 4; ++nt) {
        const int n = nt * 16 + fr;
        if (n < 60) {
          const int f0 = w * 16 + rg * 4;
          short4v p;
          #pragma unroll
          for (int j = 0; j < 4; ++j) p[j] = (short)f2bf(racc[m2 * 4 + nt][j]);
          *reinterpret_cast<short4v*>(
              &xbt[m2 * 8192 + n * 128 + (((f0 >> 3) ^ (n & 7)) << 3) + (f0 & 7)]) = p;
        }
      }
    }
  }
  __syncthreads();
}

// ---------------- MEGA: 1 block = 2 molecules, 512 threads ----------------
__global__ __launch_bounds__(512, 4) void mega(
    const float* __restrict__ atoms, const int* __restrict__ edges_g,
    const u16* __restrict__ bsum, const u16* __restrict__ wt1,
    const u16* __restrict__ wt2, const u16* __restrict__ wt3,
    const u16* __restrict__ wcf, const float* __restrict__ scale,
    const float* __restrict__ shift, const float* __restrict__ shift2,
    float* __restrict__ out) {
  __shared__ __align__(16) char smem[80160];
  u16* feats = (u16*)smem;                       // [2][60][160]; f32 atom scratch @ phase 0
  u16* xbt = (u16*)(smem + 38400);               // [2][128][64] transposed; later conv [2][60][128]
  u8* S8 = (u8*)(smem + 71168);                  // [2][64][64]
  signed char* eds = (signed char*)(smem + 79360);   // [2][300]
  u8* degs8 = (u8*)(smem + 79960);               // [2][64]
  int* presentS = (int*)(smem + 80088);          // [2]
  int* tilemask = (int*)(smem + 80096);          // [2][6]

  const int b0 = blockIdx.x * 2, tid = threadIdx.x;
  const int lane = tid & 63;
  const int w = __builtin_amdgcn_readfirstlane(tid >> 6);   // 0..7

  // ---- 0a: edges, zero S8/xbt-hi/masks, stage atoms f32 into feats scratch ----
  if (tid < 2) presentS[tid] = 0;
  if (tid >= 2 && tid < 14) tilemask[tid - 2] = 0;
  for (int i = tid; i < 600; i += 512) eds[i] = (signed char)edges_g[b0 * 300 + i];
  {
    int4 z = {0, 0, 0, 0};
    int4* sz = (int4*)S8;
    for (int i = tid; i < 512; i += 512) sz[i] = z;          // 8192 B
    int4* x0 = (int4*)(xbt + 4096);
    int4* x1 = (int4*)(xbt + 8192 + 4096);
    for (int i = tid; i < 512; i += 512) { x0[i] = z; x1[i] = z; }  // c in [64,128)
    const float4* ag = (const float4*)(atoms + (size_t)b0 * 3720);
    float4* fs0 = (float4*)feats;
    float4* fs1 = (float4*)(feats + 9600);
    for (int i = tid; i < 1860; i += 512) {
      float4 v = ag[i];
      if (i < 930) fs0[i] = v; else fs1[i - 930] = v;
    }
  }
  __syncthreads();

  // ---- 0b: pack xbt c<64 (b128 transposed writes) + S build + degrees ----
  for (int id = tid; id < 1024; id += 512) {
    int mol = id >> 9, r = id & 511;
    int oct = r & 7, c = r >> 3;                   // c 0..63
    const float* fs = (const float*)(feats + mol * 9600);
    bf16x8 v;
    #pragma unroll
    for (int k = 0; k < 8; ++k) {
      int n = oct * 8 + k;
      float x = (c < 62 && n < 60) ? fs[n * 62 + c] : 0.f;
      v[k] = (short)f2bf(x);
    }
    *reinterpret_cast<bf16x8*>(&xbt[mol * 8192 + c * 64 + ((oct ^ (c & 7)) << 3)]) = v;
  }
  if (tid < 128) {
    int mol = tid >> 6, n = tid & 63;
    int dgv = 7;
    if (n < 60) {
      dgv = 0;
      const signed char* e = eds + mol * 300 + n * 5;
      #pragma unroll
      for (int d = 0; d < 5; ++d) dgv += (e[d] >= 0);
      atomicOr(&presentS[mol], 1 << dgv);
      u8* Sm = S8 + mol * 4096;
      Sm[n * 64 + n] = (u8)(Sm[n * 64 + n] + 1);
      #pragma unroll
      for (int d = 0; d < 5; ++d) {
        int ev = e[d];
        if (ev >= 0) Sm[n * 64 + ev] = (u8)(Sm[n * 64 + ev] + 1);
      }
    }
    degs8[tid] = (u8)dgv;
  }
  __syncthreads();

  // ---- 0c: zero feats fully + per-(mol,degree,tile) masks ----
  {
    int4 z = {0, 0, 0, 0};
    int4* fz = (int4*)feats;
    for (int i = tid; i < 2400; i += 512) fz[i] = z;
  }
  if (tid < 48) {
    int m2 = tid / 24, rem = tid % 24, d = rem >> 2, nt = rem & 3;
    bool any = false;
    #pragma unroll
    for (int r = 0; r < 15; ++r) {
      int n = nt * 16 + r;
      if (n < 60 && degs8[m2 * 64 + n] == (u8)d) any = true;
    }
    { int n = nt * 16 + 15; if (n < 60 && degs8[m2 * 64 + n] == (u8)d) any = true; }
    if (any) atomicOr(&tilemask[m2 * 6 + d], 1 << nt);
  }
  __syncthreads();

  const u16* bsum2 = bsum + (size_t)b0 * 360;
  layer<1, 64, 3, false>(feats, xbt, S8, degs8, presentS, tilemask, bsum2, wt1,
                         scale + 0, shift2 + 0, tid, lane, w);
  layer<2, 128, 5, false>(feats, xbt, S8, degs8, presentS, tilemask, bsum2, wt2,
                          scale + 128, shift2 + 768, tid, lane, w);
  layer<2, 128, 5, true>(feats, xbt, S8, degs8, presentS, tilemask, bsum2, wt3,
                         scale + 256, shift2 + 1536, tid, lane, w);

  // ---- conv: implicit GEMM, both mols share the 16-f weight ring ----
  {
    const int fr = lane & 15, rg = lane >> 4;
    f32x4 cacc[2][3];
    #pragma unroll
    for (int m2 = 0; m2 < 2; ++m2)
      #pragma unroll
      for (int rt = 0; rt < 3; ++rt) cacc[m2][rt] = (f32x4){0.f, 0.f, 0.f, 0.f};

    bf16x8 br[4], ar[2][2][3];
    auto loadB = [&](int ks, int slot) {
      br[slot] = *reinterpret_cast<const bf16x8*>(
          &wcf[(((size_t)ks * 8 + w) * 64 + lane) * 8]);
    };
    auto loadA = [&](int ks, int slot) {
      int rowadd = ks >> 2;
      int unit = ((ks & 3) << 2) + rg;
      #pragma unroll
      for (int m2 = 0; m2 < 2; ++m2) {
        #pragma unroll
        for (int rt = 0; rt < 3; ++rt) {
          int arow = rt * 16 + fr + rowadd;    // <= 62; rows>=60 finite garbage, discarded
          int uo = unit ^ (arow & 7);
          ar[slot][m2][rt] = *reinterpret_cast<const bf16x8*>(
              &xbt[m2 * 8192 + arow * 128 + uo * 8]);
        }
      }
    };
    loadB(0, 0); loadB(1, 1); loadB(2, 2); loadA(0, 0);
    #pragma unroll 4
    for (int ks = 0; ks < 64; ++ks) {
      if (ks < 63) loadA(ks + 1, (ks + 1) & 1);
      #pragma unroll
      for (int m2 = 0; m2 < 2; ++m2)
        #pragma unroll
        for (int rt = 0; rt < 3; ++rt)
          cacc[m2][rt] = __builtin_amdgcn_mfma_f32_16x16x32_bf16(
              ar[ks & 1][m2][rt], br[ks & 3], cacc[m2][rt], 0, 0, 0);
      if (ks < 61) loadB(ks + 3, (ks + 3) & 3);
    }

    const int f = w * 16 + fr;
    const float sc = scale[384 + f], sh = shift[384 + f];
    #pragma unroll
    for (int m2 = 0; m2 < 2; ++m2) {
      #pragma unroll
      for (int rt = 0; rt < 3; ++rt) {
        #pragma unroll
        for (int j = 0; j < 4; ++j) {
          int t = rt * 16 + rg * 4 + j;
          if (t < 45) {
            float y = fmaxf(cacc[m2][rt][j] * sc + sh, 0.f);
            out[((size_t)(b0 + m2) * 45 + t) * 128 + f] = y;
          }
        }
      }
    }
  }
}

extern "C" void kernel_launch(void* const* d_in, const int* in_sizes, int n_in,
                              void* d_out, int out_size, void* d_ws, size_t ws_size,
                              hipStream_t stream) {
  const float* atoms = (const float*)d_in[0];
  const float* bonds = (const float*)d_in[1];
  const int*   edges = (const int*)d_in[2];
  const float* W1 = (const float*)d_in[3]; const float* b1 = (const float*)d_in[4];
  const float* W2 = (const float*)d_in[5]; const float* b2 = (const float*)d_in[6];
  const float* W3 = (const float*)d_in[7]; const float* b3 = (const float*)d_in[8];
  const float* Wc = (const float*)d_in[9];

  char* ws = (char*)d_ws;
  float* scale  = (float*)(ws + OFF_BN);
  float* shift  = scale + 512;
  float* shift2 = (float*)(ws + OFF_SH2);
  u16*   bsum   = (u16*)(ws + OFF_BSUM);
  u16*   wt1    = (u16*)(ws + OFF_WT1);
  u16*   wt2    = (u16*)(ws + OFF_WT2);
  u16*   wt3    = (u16*)(ws + OFF_WT3);
  u16*   wcf    = (u16*)(ws + OFF_WCF);

  prep<<<775, 256, 0, stream>>>(
      bonds, Wc, W1, W2, W3,
      (const float*)d_in[10], (const float*)d_in[11], (const float*)d_in[12], (const float*)d_in[13],
      (const float*)d_in[14], (const float*)d_in[15], (const float*)d_in[16], (const float*)d_in[17],
      (const float*)d_in[18], (const float*)d_in[19], (const float*)d_in[20], (const float*)d_in[21],
      (const float*)d_in[22], (const float*)d_in[23], (const float*)d_in[24], (const float*)d_in[25],
      b1, b2, b3, scale, shift, shift2, bsum, wt1, wt2, wt3, wcf);

  mega<<<512, 512, 0, stream>>>(atoms, edges, bsum, wt1, wt2, wt3, wcf,
                                scale, shift, shift2, (float*)d_out);
}